// Round 3
// baseline (22071.693 us; speedup 1.0000x reference)
//
#include <hip/hip_runtime.h>
#include <math.h>

typedef unsigned short u16;
typedef __attribute__((ext_vector_type(8))) short bf16x8;
typedef __attribute__((ext_vector_type(4))) float f32x4;

#define T_STEPS 64
#define B_      256
#define EMB_    1024
#define ACT_    6
#define STOCH_  64
#define HID_    512
#define FEAT_   512
#define STATE_  576
#define G3      1536
#define TK      32
#define LOG2PI_ 1.8378770664093453

struct Params {
  const float *emb,*action,*reward,*eps;
  const float *bih,*bhh,*stb0,*stb1,*stb2,*epb0,*epb1,*epb2;
  const u16 *bWih,*bWhh,*bstW0,*bstW1,*bstW2,*bepW0,*bepW1,*bepW2;
  const u16 *embb;        // bf16 emb [T*B][EMB]
  u16 *states;            // bf16 [T*B][STATE_]
  double *acc;            // [0]=kl [1]=emb [2]=reward
  float *out;
};

__device__ __forceinline__ float4 ld4(const float* p){ return *(const float4*)p; }
__device__ __forceinline__ float elu_f(float x){ return x > 0.f ? x : expm1f(x); }
__device__ __forceinline__ float sigmoid_f(float x){ return 1.f/(1.f+expf(-x)); }
__device__ __forceinline__ float softplus_f(float x){ return x > 20.f ? x : log1pf(expf(x)); }
__device__ __forceinline__ float blo(unsigned u){ return __uint_as_float(u << 16); }
__device__ __forceinline__ float bhi(unsigned u){ return __uint_as_float(u & 0xFFFF0000u); }
__device__ __forceinline__ u16 f2bf(float x){     // fp32 -> bf16 RNE
  const unsigned u = __float_as_uint(x);
  return (u16)((u + 0x7FFFu + ((u>>16)&1u)) >> 16);
}
__device__ __forceinline__ double wave_sum(double v){
  #pragma unroll
  for (int o = 32; o > 0; o >>= 1) v += __shfl_down(v, o, 64);
  return v;
}
__device__ __forceinline__ f32x4 MF(bf16x8 a, bf16x8 b, f32x4 c){
  return __builtin_amdgcn_mfma_f32_16x16x32_bf16(a, b, c, 0, 0, 0);
}
// B-frag from global row-major W[N][K]: col = lane&15 baked into n, k incl (lane>>4)*8
__device__ __forceinline__ bf16x8 gB(const u16* __restrict__ W, long n, int k, int K){
  return *(const bf16x8*)(W + n*K + k);
}
// Swizzled LDS bf16 scalar access. rowBytes must be a multiple of 128.
__device__ __forceinline__ void stbf(u16* buf, int row, int col, int rowBytes, u16 v){
  *(u16*)((char*)buf + row*rowBytes + ((col<<1) ^ ((row&7)<<4))) = v;
}
__device__ __forceinline__ float ldbf(const u16* buf, int row, int col, int rowBytes){
  const u16 v = *(const u16*)((const char*)buf + row*rowBytes + ((col<<1) ^ ((row&7)<<4)));
  return __uint_as_float((unsigned)v << 16);
}

// ---------------- weight converters (fp32 -> bf16 RNE) — R5-proven ----------------
__global__ void convw_k(const float* __restrict__ s, u16* __restrict__ d, int n){
  const int i = blockIdx.x*256 + threadIdx.x;
  if (i < n){
    const unsigned u = __float_as_uint(s[i]);
    d[i] = (u16)((u + 0x7FFFu + ((u>>16)&1u)) >> 16);
  }
}
// Wih [1536][70] -> padded [1536][96] bf16 (zero pad)
__global__ void convwih_k(const float* __restrict__ s, u16* __restrict__ d){
  const int i = blockIdx.x*256 + threadIdx.x;   // < 1536*96
  const int n = i/96, k = i%96;
  u16 r = 0;
  if (k < 70){
    const unsigned u = __float_as_uint(s[n*70 + k]);
    r = (u16)((u + 0x7FFFu + ((u>>16)&1u)) >> 16);
  }
  d[i] = r;
}

// ---------------- R9 MFMA scan: 16 rows/block, 16 blocks, 512 thr = 8 waves ---------
// Weight traffic drops 16x vs GEMV (each block reads each weight once per step).
// A-frag: row=lane&15, k=(lane>>4)*8+[0..7]. D-frag: col=lane&15, row=(lane>>4)*4+q.
// Activations: bf16 in LDS, XOR-swizzled (byte ^= (row&7)<<4) for ds_read_b128.
// gi/gh gate tiles live in registers from S_A to the GRU combine (no LDS).
__global__ void __launch_bounds__(512, 2) scan_kernel(Params p)
{
  const int tid = threadIdx.x;
  const int w   = tid >> 6;          // wave 0..7
  const int lane= tid & 63;
  const int lr  = lane & 15;
  const int lk8 = (lane >> 4) << 3;  // frag k offset
  const int lq4 = (lane >> 4) << 2;  // D-frag row base
  const int r0  = blockIdx.x * 16;
  const int swzA = (lr & 7) << 4;

  __shared__ __align__(16) u16 hs[16*576];     // [h(512)|s(64)] bf16, rowBytes 1152
  __shared__ __align__(16) u16 sa[16*128];     // [s(64)|a(6)|0..], rowBytes 256
  __shared__ __align__(16) u16 pemb[16*1024];  // prior emb prediction, rowBytes 2048
  __shared__ __align__(16) u16 pq[32*512];     // st0 out: rows0-15 posterior, 16-31 prior
  __shared__ __align__(16) u16 scr[32*512];    // pe0(rows0-15)|pe1(rows16-31); reused as pq1
  __shared__ __align__(16) float out2[32*128]; // st2 raw out (fp32, unswizzled)

  for (int i = tid; i < 16*576; i += 512) hs[i] = 0;
  for (int i = tid; i < 16*128; i += 512) sa[i] = 0;
  __syncthreads();

  double klacc = 0.0;

  for (int t = 0; t < T_STEPS; ++t){
    // ---- prologue: a_t -> sa cols 64..69 ----
    if (tid < 96){
      const int row = tid / 6, cc = tid - row*6;
      stbf(sa, row, 64+cc, 256, f2bf(p.action[((long)t*B_ + r0 + row)*ACT_ + cc]));
    }
    __syncthreads();

    // ---- S_A: pe0 (K=576) + gh (K=512) + gi (K=96); inputs h_{t-1}, s_{t-1} ----
    f32x4 accP[4] = {};
    f32x4 gHr[4] = {}, gHz[4] = {}, gHn[4] = {};
    f32x4 gIr[4] = {}, gIz[4] = {}, gIn[4] = {};
    for (int ks = 0; ks < 16; ++ks){
      const int k0 = ks*32 + lk8;
      const bf16x8 aA = *(const bf16x8*)((const char*)hs + lr*1152 + ((k0<<1) ^ swzA));
      #pragma unroll
      for (int nt = 0; nt < 4; ++nt){
        const long nc = w*64 + nt*16 + lr;
        accP[nt] = MF(aA, gB(p.bepW0, nc,       k0, 576), accP[nt]);
        gHr[nt]  = MF(aA, gB(p.bWhh,  nc,       k0, 512), gHr[nt]);
        gHz[nt]  = MF(aA, gB(p.bWhh,  nc+512,   k0, 512), gHz[nt]);
        gHn[nt]  = MF(aA, gB(p.bWhh,  nc+1024,  k0, 512), gHn[nt]);
      }
    }
    #pragma unroll
    for (int ks = 16; ks < 18; ++ks){     // pe0 s-tail (k 512..576)
      const int k0 = ks*32 + lk8;
      const bf16x8 aA = *(const bf16x8*)((const char*)hs + lr*1152 + ((k0<<1) ^ swzA));
      #pragma unroll
      for (int nt = 0; nt < 4; ++nt)
        accP[nt] = MF(aA, gB(p.bepW0, w*64 + nt*16 + lr, k0, 576), accP[nt]);
    }
    #pragma unroll
    for (int ks = 0; ks < 3; ++ks){       // gi from sa (K=96)
      const int k0 = ks*32 + lk8;
      const bf16x8 aA = *(const bf16x8*)((const char*)sa + lr*256 + ((k0<<1) ^ swzA));
      #pragma unroll
      for (int nt = 0; nt < 4; ++nt){
        const long nc = w*64 + nt*16 + lr;
        gIr[nt] = MF(aA, gB(p.bWih, nc,      k0, 96), gIr[nt]);
        gIz[nt] = MF(aA, gB(p.bWih, nc+512,  k0, 96), gIz[nt]);
        gIn[nt] = MF(aA, gB(p.bWih, nc+1024, k0, 96), gIn[nt]);
      }
    }
    #pragma unroll
    for (int nt = 0; nt < 4; ++nt){       // write pe0 = elu(+b) -> scr rows 0-15
      const int col = w*64 + nt*16 + lr;
      const float bv = p.epb0[col];
      #pragma unroll
      for (int q = 0; q < 4; ++q)
        stbf(scr, lq4+q, col, 1024, f2bf(elu_f(accP[nt][q] + bv)));
    }
    __syncthreads();

    // ---- S_B: GRU combine -> h_t (regs; own cols only) ; pe1 = elu(pe0.epW1^T) ----
    #pragma unroll
    for (int nt = 0; nt < 4; ++nt){
      const int col = w*64 + nt*16 + lr;
      const float bir = p.bih[col],      bhr = p.bhh[col];
      const float biz = p.bih[col+512],  bhz = p.bhh[col+512];
      const float bin = p.bih[col+1024], bhn = p.bhh[col+1024];
      #pragma unroll
      for (int q = 0; q < 4; ++q){
        const int row = lq4 + q;
        const float rr = sigmoid_f(gIr[nt][q] + bir + gHr[nt][q] + bhr);
        const float z  = sigmoid_f(gIz[nt][q] + biz + gHz[nt][q] + bhz);
        const float nn = tanhf(gIn[nt][q] + bin + rr*(gHn[nt][q] + bhn));
        const float hv = (1.f - z)*nn + z*ldbf(hs, row, col, 1152);
        const u16 hb = f2bf(hv);
        stbf(hs, row, col, 1152, hb);
        p.states[((long)t*B_ + r0 + row)*STATE_ + col] = hb;
      }
    }
    {
      f32x4 acc1[4] = {};
      for (int ks = 0; ks < 16; ++ks){
        const int k0 = ks*32 + lk8;
        const bf16x8 aA = *(const bf16x8*)((const char*)scr + lr*1024 + ((k0<<1) ^ swzA));
        #pragma unroll
        for (int nt = 0; nt < 4; ++nt)
          acc1[nt] = MF(aA, gB(p.bepW1, w*64 + nt*16 + lr, k0, 512), acc1[nt]);
      }
      #pragma unroll
      for (int nt = 0; nt < 4; ++nt){     // pe1 -> scr rows 16-31
        const int col = w*64 + nt*16 + lr;
        const float bv = p.epb1[col];
        #pragma unroll
        for (int q = 0; q < 4; ++q)
          stbf(scr, 16 + lq4+q, col, 1024, f2bf(elu_f(acc1[nt][q] + bv)));
      }
    }
    __syncthreads();

    // ---- S_C: pemb = pe1.epW2^T + b (N=1024, linear head) ----
    {
      f32x4 acc2[8] = {};
      for (int ks = 0; ks < 16; ++ks){
        const int k0 = ks*32 + lk8;
        const bf16x8 aA = *(const bf16x8*)((const char*)scr + (16+lr)*1024 + ((k0<<1) ^ swzA));
        #pragma unroll
        for (int nt = 0; nt < 8; ++nt)
          acc2[nt] = MF(aA, gB(p.bepW2, w*128 + nt*16 + lr, k0, 512), acc2[nt]);
      }
      #pragma unroll
      for (int nt = 0; nt < 8; ++nt){
        const int col = w*128 + nt*16 + lr;
        const float bv = p.epb2[col];
        #pragma unroll
        for (int q = 0; q < 4; ++q)
          stbf(pemb, lq4+q, col, 2048, f2bf(acc2[nt][q] + bv));
      }
    }
    __syncthreads();

    // ---- S_D: st0, M=32 stacked (posterior: [h_t|emb_prev], prior: [h_t|pemb]) ----
    {
      f32x4 accQ[4] = {};
      for (int ks = 0; ks < 16; ++ks){    // shared h-head (k<512), computed once
        const int k0 = ks*32 + lk8;
        const bf16x8 aA = *(const bf16x8*)((const char*)hs + lr*1152 + ((k0<<1) ^ swzA));
        #pragma unroll
        for (int nt = 0; nt < 4; ++nt)
          accQ[nt] = MF(aA, gB(p.bstW0, w*64 + nt*16 + lr, k0, 1536), accQ[nt]);
      }
      f32x4 accR[4];
      #pragma unroll
      for (int nt = 0; nt < 4; ++nt) accR[nt] = accQ[nt];
      const u16* eb = p.embb + ((long)(t > 0 ? t-1 : 0)*B_ + r0 + lr)*EMB_;
      for (int ks = 0; ks < 32; ++ks){    // tails (k 512..1536)
        const int k0 = ks*32 + lk8;
        const bf16x8 aPo = *(const bf16x8*)(eb + k0);
        const bf16x8 aPr = *(const bf16x8*)((const char*)pemb + lr*2048 + ((k0<<1) ^ swzA));
        #pragma unroll
        for (int nt = 0; nt < 4; ++nt){
          const long nc = w*64 + nt*16 + lr;
          const bf16x8 bW = gB(p.bstW0, nc, 512 + k0, 1536);
          accQ[nt] = MF(aPo, bW, accQ[nt]);
          accR[nt] = MF(aPr, bW, accR[nt]);
        }
      }
      #pragma unroll
      for (int nt = 0; nt < 4; ++nt){
        const int col = w*64 + nt*16 + lr;
        const float bv = p.stb0[col];
        #pragma unroll
        for (int q = 0; q < 4; ++q){
          stbf(pq, lq4+q,     col, 1024, f2bf(elu_f(accQ[nt][q] + bv)));
          stbf(pq, 16+lq4+q,  col, 1024, f2bf(elu_f(accR[nt][q] + bv)));
        }
      }
    }
    __syncthreads();

    // ---- S_E: st1, M=32 (B-frag shared across both M-tiles) -> pq1 (= scr) ----
    {
      f32x4 accS0[4] = {}, accS1[4] = {};
      for (int ks = 0; ks < 16; ++ks){
        const int k0 = ks*32 + lk8;
        const bf16x8 a0 = *(const bf16x8*)((const char*)pq + lr*1024      + ((k0<<1) ^ swzA));
        const bf16x8 a1 = *(const bf16x8*)((const char*)pq + (16+lr)*1024 + ((k0<<1) ^ swzA));
        #pragma unroll
        for (int nt = 0; nt < 4; ++nt){
          const bf16x8 bW = gB(p.bstW1, w*64 + nt*16 + lr, k0, 512);
          accS0[nt] = MF(a0, bW, accS0[nt]);
          accS1[nt] = MF(a1, bW, accS1[nt]);
        }
      }
      #pragma unroll
      for (int nt = 0; nt < 4; ++nt){
        const int col = w*64 + nt*16 + lr;
        const float bv = p.stb1[col];
        #pragma unroll
        for (int q = 0; q < 4; ++q){
          stbf(scr, lq4+q,     col, 1024, f2bf(elu_f(accS0[nt][q] + bv)));
          stbf(scr, 16+lq4+q,  col, 1024, f2bf(elu_f(accS1[nt][q] + bv)));
        }
      }
    }
    __syncthreads();

    // ---- S_F: st2, N=128 (wave w -> cols w*16..+16) -> out2 fp32 ----
    {
      f32x4 accT0 = {0.f,0.f,0.f,0.f}, accT1 = {0.f,0.f,0.f,0.f};
      for (int ks = 0; ks < 16; ++ks){
        const int k0 = ks*32 + lk8;
        const bf16x8 a0 = *(const bf16x8*)((const char*)scr + lr*1024      + ((k0<<1) ^ swzA));
        const bf16x8 a1 = *(const bf16x8*)((const char*)scr + (16+lr)*1024 + ((k0<<1) ^ swzA));
        const bf16x8 bW = gB(p.bstW2, w*16 + lr, k0, 512);
        accT0 = MF(a0, bW, accT0);
        accT1 = MF(a1, bW, accT1);
      }
      const int col = w*16 + lr;
      const float bv = p.stb2[col];
      #pragma unroll
      for (int q = 0; q < 4; ++q){
        out2[(lq4+q)*128 + col]    = accT0[q] + bv;
        out2[(16+lq4+q)*128 + col] = accT1[q] + bv;
      }
    }
    __syncthreads();

    // ---- S_G: KL(t) + sample s_t (512 thr x 2 elems) ----
    {
      const int row = tid >> 5;
      const int j0  = (tid & 31) * 2;
      #pragma unroll
      for (int u = 0; u < 2; ++u){
        const int j = j0 + u;
        const float qmu = out2[row*128 + j],      qsr = out2[row*128 + 64 + j];
        const float pmu = out2[(16+row)*128 + j], psr = out2[(16+row)*128 + 64 + j];
        const float qstd = softplus_f(qsr) + 1e-4f;
        const float pstd = softplus_f(psr) + 1e-4f;
        const float dm = qmu - pmu;
        klacc += (double)(logf(pstd/qstd) + (qstd*qstd + dm*dm)/(2.f*pstd*pstd) - 0.5f);
        const float sv = qmu + qstd * p.eps[((long)t*B_ + r0 + row)*STOCH_ + j];
        const u16 sb = f2bf(sv);
        stbf(hs, row, 512 + j, 1152, sb);
        stbf(sa, row, j, 256, sb);
        p.states[((long)t*B_ + r0 + row)*STATE_ + 512 + j] = sb;
      }
    }
    __syncthreads();
  }

  const double s = wave_sum(klacc);
  if (lane == 0) atomicAdd(&p.acc[0], s);
}

// ---------------- MFMA bf16 tail GEMMs (R8-proven, byte-identical) ------------------

__global__ void __launch_bounds__(256) gemm_h_k(const u16* __restrict__ A,
                                                const u16* __restrict__ W,
                                                const float* __restrict__ bias,
                                                u16* __restrict__ Y,
                                                int NT, int K, int act)
{
  const int tid = threadIdx.x;
  const int wave = tid >> 6, lane = tid & 63;
  const int bm = blockIdx.x / NT, bn = blockIdx.x % NT;
  const int row0 = bm*128 + ((wave>>1)<<6);
  const int col0 = bn*128 + ((wave&1)<<6);
  const int lr = lane & 15, lk = (lane >> 4) * 8;
  const int N = NT << 7;
  f32x4 acc[4][4] = {};
  const u16* Ab = A + (long)row0*K + lk;
  const u16* Wb = W + (long)col0*K + lk;
  for (int k0 = 0; k0 < K; k0 += 32){
    bf16x8 a[4], b[4];
    #pragma unroll
    for (int i = 0; i < 4; ++i) a[i] = *(const bf16x8*)(Ab + (long)(16*i+lr)*K + k0);
    #pragma unroll
    for (int j = 0; j < 4; ++j) b[j] = *(const bf16x8*)(Wb + (long)(16*j+lr)*K + k0);
    #pragma unroll
    for (int i = 0; i < 4; ++i)
      #pragma unroll
      for (int j = 0; j < 4; ++j)
        acc[i][j] = __builtin_amdgcn_mfma_f32_16x16x32_bf16(a[i], b[j], acc[i][j], 0, 0, 0);
  }
  #pragma unroll
  for (int j = 0; j < 4; ++j){
    const int col = col0 + 16*j + lr;
    const float bv = bias[col];
    #pragma unroll
    for (int i = 0; i < 4; ++i){
      #pragma unroll
      for (int q = 0; q < 4; ++q){
        const int row = row0 + 16*i + (lane>>4)*4 + q;
        float v = acc[i][j][q] + bv;
        if (act) v = elu_f(v);
        Y[(long)row*N + col] = f2bf(v);
      }
    }
  }
}

__device__ __forceinline__ double wave_sum_d(double v){
  #pragma unroll
  for (int o = 32; o > 0; o >>= 1) v += __shfl_down(v, o, 64);
  return v;
}

__global__ void __launch_bounds__(256) gemm_loss_k(const u16* __restrict__ A,
                                                   const u16* __restrict__ W,
                                                   const float* __restrict__ bias,
                                                   const float* __restrict__ tgt,
                                                   int NT, int K, double* accp)
{
  const int tid = threadIdx.x;
  const int wave = tid >> 6, lane = tid & 63;
  const int bm = blockIdx.x / NT, bn = blockIdx.x % NT;
  const int row0 = bm*128 + ((wave>>1)<<6);
  const int col0 = bn*128 + ((wave&1)<<6);
  const int lr = lane & 15, lk = (lane >> 4) * 8;
  const int N = NT << 7;
  f32x4 acc[4][4] = {};
  const u16* Ab = A + (long)row0*K + lk;
  const u16* Wb = W + (long)col0*K + lk;
  for (int k0 = 0; k0 < K; k0 += 32){
    bf16x8 a[4], b[4];
    #pragma unroll
    for (int i = 0; i < 4; ++i) a[i] = *(const bf16x8*)(Ab + (long)(16*i+lr)*K + k0);
    #pragma unroll
    for (int j = 0; j < 4; ++j) b[j] = *(const bf16x8*)(Wb + (long)(16*j+lr)*K + k0);
    #pragma unroll
    for (int i = 0; i < 4; ++i)
      #pragma unroll
      for (int j = 0; j < 4; ++j)
        acc[i][j] = __builtin_amdgcn_mfma_f32_16x16x32_bf16(a[i], b[j], acc[i][j], 0, 0, 0);
  }
  double ls = 0.0;
  #pragma unroll
  for (int j = 0; j < 4; ++j){
    const int col = col0 + 16*j + lr;
    const float bv = bias[col];
    #pragma unroll
    for (int i = 0; i < 4; ++i){
      #pragma unroll
      for (int q = 0; q < 4; ++q){
        const int row = row0 + 16*i + (lane>>4)*4 + q;
        const float d = tgt[(long)row*N + col] - (acc[i][j][q] + bv);
        ls += 0.5 * (double)d * (double)d;
      }
    }
  }
  ls = wave_sum_d(ls);
  if (lane == 0) atomicAdd(accp, ls);
}

__global__ void __launch_bounds__(512) rp_loss_b(const u16* __restrict__ h2,
                                                 const float* __restrict__ W2,
                                                 const float* __restrict__ b2,
                                                 const float* __restrict__ reward,
                                                 double* accp)
{
  const int tid = threadIdx.x;
  const int lane = tid & 63;
  const int wid = blockIdx.x*8 + (tid >> 6);
  double ls = 0.0;
  for (int row = wid; row < T_STEPS*B_; row += 2048) {
    const uint4 hv = *(const uint4*)(h2 + (long)row*FEAT_ + lane*8);
    const float4 w0 = ld4(W2 + lane*8);
    const float4 w1 = ld4(W2 + lane*8 + 4);
    float part = blo(hv.x)*w0.x + bhi(hv.x)*w0.y + blo(hv.y)*w0.z + bhi(hv.y)*w0.w
               + blo(hv.z)*w1.x + bhi(hv.z)*w1.y + blo(hv.w)*w1.z + bhi(hv.w)*w1.w;
    #pragma unroll
    for (int o = 32; o > 0; o >>= 1) part += __shfl_down(part, o, 64);
    if (lane == 0) {
      const float mu = part + b2[0];
      const float d = reward[row] - mu;
      ls += 0.5 * (double)d * (double)d;
    }
  }
  if (lane == 0) atomicAdd(accp, ls);
}

__global__ void final_k(const double* acc, float* out)
{
  const double tot = (acc[0] + acc[1] + acc[2]) / (double)(T_STEPS * B_)
                   + 512.0 * LOG2PI_ + 0.5 * LOG2PI_;
  out[0] = (float)tot;
}

extern "C" void kernel_launch(void* const* d_in, const int* in_sizes, int n_in,
                              void* d_out, int out_size, void* d_ws, size_t ws_size,
                              hipStream_t stream) {
  const float* emb    = (const float*)d_in[0];
  const float* action = (const float*)d_in[1];
  const float* reward = (const float*)d_in[2];
  const float* eps    = (const float*)d_in[3];
  const float* Wih  = (const float*)d_in[4];  const float* bih  = (const float*)d_in[5];
  const float* Whh  = (const float*)d_in[6];  const float* bhh  = (const float*)d_in[7];
  const float* stW0 = (const float*)d_in[8];  const float* stb0 = (const float*)d_in[9];
  const float* stW1 = (const float*)d_in[10]; const float* stb1 = (const float*)d_in[11];
  const float* stW2 = (const float*)d_in[12]; const float* stb2 = (const float*)d_in[13];
  const float* epW0 = (const float*)d_in[14]; const float* epb0 = (const float*)d_in[15];
  const float* epW1 = (const float*)d_in[16]; const float* epb1 = (const float*)d_in[17];
  const float* epW2 = (const float*)d_in[18]; const float* epb2 = (const float*)d_in[19];
  const float* rpW0 = (const float*)d_in[20]; const float* rpb0 = (const float*)d_in[21];
  const float* rpW1 = (const float*)d_in[22]; const float* rpb1 = (const float*)d_in[23];
  const float* rpW2 = (const float*)d_in[24]; const float* rpb2 = (const float*)d_in[25];

  double* acc = (double*)d_ws;
  // bf16 workspace layout (~60 MiB total, all 16B-aligned).
  // embb (16384*1024) ALIASES h1b+h2b: scan consumes embb, tail then reuses as h1/h2.
  u16* states_b = (u16*)((char*)d_ws + 256);          // 16384*576
  u16* h1b = states_b + (long)16384*STATE_;           // 16384*512
  u16* h2b = h1b + (long)16384*FEAT_;                 // 16384*512
  u16* embb = h1b;                                    // 16384*1024 (= h1b..h2b span)
  u16* bw  = h2b + (long)16384*FEAT_;
  u16* bepW0 = bw;    bw += 294912;
  u16* bepW1 = bw;    bw += 262144;
  u16* bepW2 = bw;    bw += 524288;
  u16* bWhh  = bw;    bw += 786432;
  u16* bstW0 = bw;    bw += 786432;
  u16* bstW1 = bw;    bw += 262144;
  u16* bstW2 = bw;    bw += 65536;
  u16* bWih  = bw;    bw += 147456;
  u16* brpW0 = bw;    bw += 294912;
  u16* brpW1 = bw;    bw += 262144;

  hipMemsetAsync(d_ws, 0, 256, stream);

  convw_k<<<(294912+255)/256, 256, 0, stream>>>(epW0, bepW0, 294912);
  convw_k<<<(262144+255)/256, 256, 0, stream>>>(epW1, bepW1, 262144);
  convw_k<<<(524288+255)/256, 256, 0, stream>>>(epW2, bepW2, 524288);
  convw_k<<<(786432+255)/256, 256, 0, stream>>>(Whh,  bWhh,  786432);
  convw_k<<<(786432+255)/256, 256, 0, stream>>>(stW0, bstW0, 786432);
  convw_k<<<(262144+255)/256, 256, 0, stream>>>(stW1, bstW1, 262144);
  convw_k<<<(65536+255)/256,  256, 0, stream>>>(stW2, bstW2, 65536);
  convwih_k<<<(147456+255)/256, 256, 0, stream>>>(Wih, bWih);
  convw_k<<<(294912+255)/256, 256, 0, stream>>>(rpW0, brpW0, 294912);
  convw_k<<<(262144+255)/256, 256, 0, stream>>>(rpW1, brpW1, 262144);
  convw_k<<<(16777216+255)/256, 256, 0, stream>>>(emb, embb, 16777216);   // emb -> bf16

  Params p;
  p.emb = emb; p.action = action; p.reward = reward; p.eps = eps;
  p.bih = bih; p.bhh = bhh;
  p.stb0 = stb0; p.stb1 = stb1; p.stb2 = stb2;
  p.epb0 = epb0; p.epb1 = epb1; p.epb2 = epb2;
  p.bWih = bWih; p.bWhh = bWhh;
  p.bstW0 = bstW0; p.bstW1 = bstW1; p.bstW2 = bstW2;
  p.bepW0 = bepW0; p.bepW1 = bepW1; p.bepW2 = bepW2;
  p.embb = embb;
  p.states = states_b;
  p.acc = acc;
  p.out = (float*)d_out;

  scan_kernel<<<16, 512, 0, stream>>>(p);

  // ---- ep chain: states -> h1 -> h2 -> emb loss (M=16384); overwrites embb ----
  gemm_h_k<<<128*4, 256, 0, stream>>>(states_b, bepW0, epb0, h1b, 4, STATE_, 1);
  gemm_h_k<<<128*4, 256, 0, stream>>>(h1b,      bepW1, epb1, h2b, 4, FEAT_, 1);
  gemm_loss_k<<<128*8, 256, 0, stream>>>(h2b, bepW2, epb2, emb, 8, FEAT_, acc + 1);
  // ---- rp chain: states -> g1 -> g2 -> reward loss (reuses h1b/h2b) ----
  gemm_h_k<<<128*4, 256, 0, stream>>>(states_b, brpW0, rpb0, h1b, 4, STATE_, 1);
  gemm_h_k<<<128*4, 256, 0, stream>>>(h1b,      brpW1, rpb1, h2b, 4, FEAT_, 1);
  rp_loss_b<<<256, 512, 0, stream>>>(h2b, rpW2, rpb2, reward, acc + 2);

  final_k<<<1, 1, 0, stream>>>(acc, p.out);
}

// Round 4
// 7837.955 us; speedup vs baseline: 2.8160x; 2.8160x over previous
//
#include <hip/hip_runtime.h>
#include <math.h>

typedef unsigned short u16;
typedef __attribute__((ext_vector_type(8))) short bf16x8;
typedef __attribute__((ext_vector_type(4))) float f32x4;

#define T_STEPS 64
#define B_      256
#define EMB_    1024
#define ACT_    6
#define STOCH_  64
#define HID_    512
#define FEAT_   512
#define STATE_  576
#define G3      1536
#define LOG2PI_ 1.8378770664093453

struct Params {
  const float *emb,*action,*reward,*eps;
  const float *bih,*bhh,*stb0,*stb1,*stb2,*epb0,*epb1,*epb2;
  const u16 *bWih,*bWhh,*bstW0,*bstW1,*bstW2,*bepW0,*bepW1,*bepW2;
  u16 *states;            // bf16 [T*B][STATE_]
  float *qraw;            // [T*B][128]: qmu(64) | qstd(64, post-softplus)
  double *acc;            // [0]=kl [1]=emb [2]=reward
  float *out;
};

__device__ __forceinline__ float4 ld4(const float* p){ return *(const float4*)p; }
__device__ __forceinline__ float elu_f(float x){ return x > 0.f ? x : expm1f(x); }
__device__ __forceinline__ float sigmoid_f(float x){ return 1.f/(1.f+expf(-x)); }
__device__ __forceinline__ float softplus_f(float x){ return x > 20.f ? x : log1pf(expf(x)); }
__device__ __forceinline__ float blo(unsigned u){ return __uint_as_float(u << 16); }
__device__ __forceinline__ float bhi(unsigned u){ return __uint_as_float(u & 0xFFFF0000u); }
__device__ __forceinline__ u16 f2bf(float x){     // fp32 -> bf16 RNE
  const unsigned u = __float_as_uint(x);
  return (u16)((u + 0x7FFFu + ((u>>16)&1u)) >> 16);
}
__device__ __forceinline__ float qred(float a){   // reduce over 4-lane cluster
  a += __shfl_xor(a, 1, 64);
  a += __shfl_xor(a, 2, 64);
  return a;
}
__device__ __forceinline__ double wave_sum(double v){
  #pragma unroll
  for (int o = 32; o > 0; o >>= 1) v += __shfl_down(v, o, 64);
  return v;
}

// ---------------- weight converters (fp32 -> bf16 RNE) — R5-proven ----------------
__global__ void convw_k(const float* __restrict__ s, u16* __restrict__ d, int n){
  const int i = blockIdx.x*256 + threadIdx.x;
  if (i < n){
    const unsigned u = __float_as_uint(s[i]);
    d[i] = (u16)((u + 0x7FFFu + ((u>>16)&1u)) >> 16);
  }
}
// Wih [1536][70] -> padded [1536][96] bf16 (zero pad)
__global__ void convwih_k(const float* __restrict__ s, u16* __restrict__ d){
  const int i = blockIdx.x*256 + threadIdx.x;   // < 1536*96
  const int n = i/96, k = i%96;
  u16 r = 0;
  if (k < 70){
    const unsigned u = __float_as_uint(s[n*70 + k]);
    r = (u16)((u + 0x7FFFu + ((u>>16)&1u)) >> 16);
  }
  d[i] = r;
}

// ---------------- scan GEMV cores: bf16 W via uint4 loads, fp32 x/accum ----------------
// 4-lane cluster, TWO output rows n0,n1 per pass sharing one x stream.
// lane l covers k = l*8 + 32*j; uint4 = 8 bf16: u32 low half = element k (LE).

template<int K>
__device__ __forceinline__ void gemv2b(const u16* __restrict__ W, const float* x,
                                       int n0, int n1, int l, float& y0, float& y1){
  const u16* w0 = W + (long)n0*K + l*8;
  const u16* w1 = W + (long)n1*K + l*8;
  const float* xr = x + l*8;
  float p0=0.f,p1=0.f,p2=0.f,p3=0.f, q0=0.f,q1=0.f,q2=0.f,q3=0.f;
  for (int j = 0; j < K/32; ++j){
    const uint4 a = *(const uint4*)(w0 + 32*j);
    const uint4 b = *(const uint4*)(w1 + 32*j);
    const float4 xa = ld4(xr + 32*j);
    const float4 xb = ld4(xr + 32*j + 4);
    p0 += blo(a.x)*xa.x + bhi(a.x)*xa.y;
    p1 += blo(a.y)*xa.z + bhi(a.y)*xa.w;
    p2 += blo(a.z)*xb.x + bhi(a.z)*xb.y;
    p3 += blo(a.w)*xb.z + bhi(a.w)*xb.w;
    q0 += blo(b.x)*xa.x + bhi(b.x)*xa.y;
    q1 += blo(b.y)*xa.z + bhi(b.y)*xa.w;
    q2 += blo(b.z)*xb.x + bhi(b.z)*xb.y;
    q3 += blo(b.w)*xb.z + bhi(b.w)*xb.w;
  }
  y0 = qred((p0+p1)+(p2+p3));
  y1 = qred((q0+q1)+(q2+q3));
}

// st0 posterior: K=1536 = 512 head (x = h_t) + 1024 tail (x = emb_prev)
__device__ __forceinline__ void st0p(const u16* __restrict__ W, const float* xh,
                                     const float* xA, int n0, int n1, int l,
                                     float& y0, float& y1){
  const u16* w0 = W + (long)n0*G3 + l*8;
  const u16* w1 = W + (long)n1*G3 + l*8;
  float h0=0.f, h1=0.f;
  for (int j = 0; j < 16; ++j){
    const uint4 a = *(const uint4*)(w0 + 32*j);
    const uint4 b = *(const uint4*)(w1 + 32*j);
    const float4 xa = ld4(xh + l*8 + 32*j);
    const float4 xb = ld4(xh + l*8 + 32*j + 4);
    h0 += blo(a.x)*xa.x + bhi(a.x)*xa.y + blo(a.y)*xa.z + bhi(a.y)*xa.w
        + blo(a.z)*xb.x + bhi(a.z)*xb.y + blo(a.w)*xb.z + bhi(a.w)*xb.w;
    h1 += blo(b.x)*xa.x + bhi(b.x)*xa.y + blo(b.y)*xa.z + bhi(b.y)*xa.w
        + blo(b.z)*xb.x + bhi(b.z)*xb.y + blo(b.w)*xb.z + bhi(b.w)*xb.w;
  }
  for (int j = 0; j < 32; ++j){
    const uint4 a = *(const uint4*)(w0 + 512 + 32*j);
    const uint4 b = *(const uint4*)(w1 + 512 + 32*j);
    const float4 va = ld4(xA + l*8 + 32*j);
    const float4 vb = ld4(xA + l*8 + 32*j + 4);
    h0 += blo(a.x)*va.x + bhi(a.x)*va.y + blo(a.y)*va.z + bhi(a.y)*va.w
        + blo(a.z)*vb.x + bhi(a.z)*vb.y + blo(a.w)*vb.z + bhi(a.w)*vb.w;
    h1 += blo(b.x)*va.x + bhi(b.x)*va.y + blo(b.y)*va.z + bhi(b.y)*va.w
        + blo(b.z)*vb.x + bhi(b.z)*vb.y + blo(b.w)*vb.z + bhi(b.w)*vb.w;
  }
  y0 = qred(h0);
  y1 = qred(h1);
}

// ---------------- scan kernel: R6-proven structure, posterior-only ------------------
// R10: prior branch (pe0/pe1/pemb + prior st chain) deferred to the MFMA tail —
// it never feeds the recurrence. Scan weight stream/step: 6.25 -> 4.1 MB.
__global__ void __launch_bounds__(512) scan_kernel(Params p)
{
  const int tid = threadIdx.x;
  const int r = blockIdx.x;
  const int c = tid >> 2, l = tid & 3;   // 128 clusters of 4 lanes

  __shared__ __align__(16) float hs[STATE_];   // [h(512) | s(64)]
  __shared__ __align__(16) float sa[96];       // [s(64) | a(6) | 0-pad]
  __shared__ __align__(16) float ep_[EMB_];
  __shared__ __align__(16) float gi[G3], gh[G3];
  __shared__ __align__(16) float po0[512], po1[512];
  __shared__ __align__(16) float po2[128];

  hs[tid] = 0.f;
  if (tid < 64) hs[512 + tid] = 0.f;
  __syncthreads();

  for (int t = 0; t < T_STEPS; ++t){
    // ---- prologue: emb_prev row + sa = [s_{t-1} | a_t | 0] ----
    {
      const long eb = ((long)(t > 0 ? t-1 : 0)*B_ + r)*EMB_;
      ep_[tid]       = p.emb[eb + tid];
      ep_[tid + 512] = p.emb[eb + 512 + tid];
      if (tid < 96){
        float v = 0.f;
        if (tid < 64)      v = hs[512 + tid];
        else if (tid < 70) v = p.action[((long)t*B_ + r)*ACT_ + (tid - 64)];
        sa[tid] = v;
      }
    }
    __syncthreads();
    // ---- S_A: gh (6p), gi (6p) — read h/s_{t-1} ----
    for (int ps = 0; ps < 6; ++ps){
      const int n0 = ps*256 + c, n1 = n0 + 128;
      float y0, y1;
      gemv2b<HID_>(p.bWhh, hs, n0, n1, l, y0, y1);
      if (l == 0){
        gh[n0] = y0 + p.bhh[n0];
        gh[n1] = y1 + p.bhh[n1];
      }
    }
    for (int ps = 0; ps < 6; ++ps){
      const int n0 = ps*256 + c, n1 = n0 + 128;
      float y0, y1;
      gemv2b<96>(p.bWih, sa, n0, n1, l, y0, y1);
      if (l == 0){
        gi[n0] = y0 + p.bih[n0];
        gi[n1] = y1 + p.bih[n1];
      }
    }
    __syncthreads();
    // ---- GRU combine -> h_t ----
    {
      const int j = tid;
      const float ir = gi[j], iz = gi[512+j], in_ = gi[1024+j];
      const float hr = gh[j], hz = gh[512+j], hn  = gh[1024+j];
      const float rr = sigmoid_f(ir + hr);
      const float z  = sigmoid_f(iz + hz);
      const float nn = tanhf(in_ + rr*hn);
      const float hv = (1.f - z)*nn + z*hs[j];
      hs[j] = hv;
      p.states[((long)t*B_ + r)*STATE_ + j] = f2bf(hv);
    }
    __syncthreads();
    // ---- S_D: st0 posterior (2p) ----
    for (int ps = 0; ps < 2; ++ps){
      const int n0 = ps*256 + c, n1 = n0 + 128;
      float y0, y1;
      st0p(p.bstW0, hs, ep_, n0, n1, l, y0, y1);
      if (l == 0){
        po0[n0] = elu_f(y0 + p.stb0[n0]);
        po0[n1] = elu_f(y1 + p.stb0[n1]);
      }
    }
    __syncthreads();
    // ---- S_E: st1 posterior (2p) ----
    for (int ps = 0; ps < 2; ++ps){
      const int n0 = ps*256 + c, n1 = n0 + 128;
      float y0, y1;
      gemv2b<FEAT_>(p.bstW1, po0, n0, n1, l, y0, y1);
      if (l == 0){
        po1[n0] = elu_f(y0 + p.stb1[n0]);
        po1[n1] = elu_f(y1 + p.stb1[n1]);
      }
    }
    __syncthreads();
    // ---- S_F: st2 posterior (1p, clusters 0..63) ----
    if (c < 64){
      const int n0 = c, n1 = c + 64;
      float y0, y1;
      gemv2b<FEAT_>(p.bstW2, po1, n0, n1, l, y0, y1);
      if (l == 0){
        po2[n0] = y0 + p.stb2[n0];
        po2[n1] = y1 + p.stb2[n1];
      }
    }
    __syncthreads();
    // ---- S_G: sample s_t, store qmu/qstd ----
    if (tid < 64){
      const int j = tid;
      const float qmu = po2[j],  qsr = po2[64+j];
      const float qstd = softplus_f(qsr) + 1e-4f;
      const float sv = qmu + qstd * p.eps[((long)t*B_ + r)*STOCH_ + j];
      hs[512 + j] = sv;
      p.states[((long)t*B_ + r)*STATE_ + 512 + j] = f2bf(sv);
      p.qraw[((long)t*B_ + r)*128 + j]      = qmu;
      p.qraw[((long)t*B_ + r)*128 + 64 + j] = qstd;
    }
    __syncthreads();
  }
}

// ---------------- MFMA bf16 tail GEMMs (R8-proven skeleton) -------------------------
// A-frag: row=lane&15, k=(lane>>4)*8+[0..7]. D-frag: col=lane&15, row=(lane>>4)*4+q.

__global__ void __launch_bounds__(256) gemm_h_k(const u16* __restrict__ A,
                                                const u16* __restrict__ W,
                                                const float* __restrict__ bias,
                                                u16* __restrict__ Y,
                                                int NT, int K, int act, int zlo)
{
  const int tid = threadIdx.x;
  const int wave = tid >> 6, lane = tid & 63;
  const int bm = blockIdx.x / NT, bn = blockIdx.x % NT;
  const int row0 = bm*128 + ((wave>>1)<<6);
  const int col0 = bn*128 + ((wave&1)<<6);
  const int lr = lane & 15, lk = (lane >> 4) * 8;
  const int N = NT << 7;
  f32x4 acc[4][4] = {};
  const u16* Ab = A + (long)row0*K + lk;
  const u16* Wb = W + (long)col0*K + lk;
  const bf16x8 zf = {};
  for (int k0 = 0; k0 < K; k0 += 32){
    bf16x8 a[4], b[4];
    #pragma unroll
    for (int i = 0; i < 4; ++i)
      a[i] = (row0 + 16*i >= zlo) ? *(const bf16x8*)(Ab + (long)(16*i+lr)*K + k0) : zf;
    #pragma unroll
    for (int j = 0; j < 4; ++j) b[j] = *(const bf16x8*)(Wb + (long)(16*j+lr)*K + k0);
    #pragma unroll
    for (int i = 0; i < 4; ++i)
      #pragma unroll
      for (int j = 0; j < 4; ++j)
        acc[i][j] = __builtin_amdgcn_mfma_f32_16x16x32_bf16(a[i], b[j], acc[i][j], 0, 0, 0);
  }
  #pragma unroll
  for (int j = 0; j < 4; ++j){
    const int col = col0 + 16*j + lr;
    const float bv = bias[col];
    #pragma unroll
    for (int i = 0; i < 4; ++i){
      #pragma unroll
      for (int q = 0; q < 4; ++q){
        const int row = row0 + 16*i + (lane>>4)*4 + q;
        float v = acc[i][j][q] + bv;
        if (act) v = elu_f(v);
        Y[(long)row*N + col] = f2bf(v);
      }
    }
  }
}

// st0 prior: A = [states.h (ld 576, k<512) | pemb (ld 1024, k>=512)], W [512][1536], elu out
__global__ void __launch_bounds__(256) gemm_cat_k(const u16* __restrict__ A1,
                                                  const u16* __restrict__ A2,
                                                  const u16* __restrict__ W,
                                                  const float* __restrict__ bias,
                                                  u16* __restrict__ Y)
{
  const int NT = 4;
  const int tid = threadIdx.x;
  const int wave = tid >> 6, lane = tid & 63;
  const int bm = blockIdx.x / NT, bn = blockIdx.x % NT;
  const int row0 = bm*128 + ((wave>>1)<<6);
  const int col0 = bn*128 + ((wave&1)<<6);
  const int lr = lane & 15, lk = (lane >> 4) * 8;
  f32x4 acc[4][4] = {};
  for (int k0 = 0; k0 < G3; k0 += 32){
    bf16x8 a[4], b[4];
    #pragma unroll
    for (int i = 0; i < 4; ++i){
      const long row = row0 + 16*i + lr;
      a[i] = (k0 < 512) ? *(const bf16x8*)(A1 + row*STATE_ + k0 + lk)
                        : *(const bf16x8*)(A2 + row*EMB_ + (k0-512) + lk);
    }
    #pragma unroll
    for (int j = 0; j < 4; ++j)
      b[j] = *(const bf16x8*)(W + (long)(col0+16*j+lr)*G3 + k0 + lk);
    #pragma unroll
    for (int i = 0; i < 4; ++i)
      #pragma unroll
      for (int j = 0; j < 4; ++j)
        acc[i][j] = __builtin_amdgcn_mfma_f32_16x16x32_bf16(a[i], b[j], acc[i][j], 0, 0, 0);
  }
  #pragma unroll
  for (int j = 0; j < 4; ++j){
    const int col = col0 + 16*j + lr;
    const float bv = bias[col];
    #pragma unroll
    for (int i = 0; i < 4; ++i){
      #pragma unroll
      for (int q = 0; q < 4; ++q){
        const int row = row0 + 16*i + (lane>>4)*4 + q;
        Y[(long)row*FEAT_ + col] = f2bf(elu_f(acc[i][j][q] + bv));
      }
    }
  }
}

// st2 prior: N=128, K=512, raw f32 out (+bias, no act). grid = M/128 blocks.
__global__ void __launch_bounds__(256) gemm_raw_k(const u16* __restrict__ A,
                                                  const u16* __restrict__ W,
                                                  const float* __restrict__ bias,
                                                  float* __restrict__ Y)
{
  const int tid = threadIdx.x;
  const int wave = tid >> 6, lane = tid & 63;
  const int row0 = blockIdx.x*128 + ((wave>>1)<<6);
  const int col0 = (wave&1)<<6;
  const int lr = lane & 15, lk = (lane >> 4) * 8;
  f32x4 acc[4][4] = {};
  const u16* Ab = A + (long)row0*FEAT_ + lk;
  const u16* Wb = W + (long)col0*FEAT_ + lk;
  for (int k0 = 0; k0 < FEAT_; k0 += 32){
    bf16x8 a[4], b[4];
    #pragma unroll
    for (int i = 0; i < 4; ++i) a[i] = *(const bf16x8*)(Ab + (long)(16*i+lr)*FEAT_ + k0);
    #pragma unroll
    for (int j = 0; j < 4; ++j) b[j] = *(const bf16x8*)(Wb + (long)(16*j+lr)*FEAT_ + k0);
    #pragma unroll
    for (int i = 0; i < 4; ++i)
      #pragma unroll
      for (int j = 0; j < 4; ++j)
        acc[i][j] = __builtin_amdgcn_mfma_f32_16x16x32_bf16(a[i], b[j], acc[i][j], 0, 0, 0);
  }
  #pragma unroll
  for (int j = 0; j < 4; ++j){
    const int col = col0 + 16*j + lr;
    const float bv = bias[col];
    #pragma unroll
    for (int i = 0; i < 4; ++i){
      #pragma unroll
      for (int q = 0; q < 4; ++q){
        const int row = row0 + 16*i + (lane>>4)*4 + q;
        Y[(long)row*128 + col] = acc[i][j][q] + bv;
      }
    }
  }
}

// KL over one 4096-row chunk: q = stored qmu/qstd, pr = prior raw (pmu, psr).
__global__ void __launch_bounds__(512) kl_k(const float* __restrict__ q,
                                            const float* __restrict__ pr,
                                            double* accp)
{
  const int idx = blockIdx.x*512 + threadIdx.x;   // < 4096*64
  const int row = idx >> 6, j = idx & 63;
  const float qmu = q[row*128 + j], qstd = q[row*128 + 64 + j];
  const float pmu = pr[row*128 + j], psr = pr[row*128 + 64 + j];
  const float pstd = softplus_f(psr) + 1e-4f;
  const float dm = qmu - pmu;
  double v = (double)(logf(pstd/qstd) + (qstd*qstd + dm*dm)/(2.f*pstd*pstd) - 0.5f);
  v = wave_sum(v);
  if ((threadIdx.x & 63) == 0) atomicAdd(accp, v);
}

__device__ __forceinline__ double wave_sum_d(double v){
  #pragma unroll
  for (int o = 32; o > 0; o >>= 1) v += __shfl_down(v, o, 64);
  return v;
}

__global__ void __launch_bounds__(256) gemm_loss_k(const u16* __restrict__ A,
                                                   const u16* __restrict__ W,
                                                   const float* __restrict__ bias,
                                                   const float* __restrict__ tgt,
                                                   int NT, int K, double* accp)
{
  const int tid = threadIdx.x;
  const int wave = tid >> 6, lane = tid & 63;
  const int bm = blockIdx.x / NT, bn = blockIdx.x % NT;
  const int row0 = bm*128 + ((wave>>1)<<6);
  const int col0 = bn*128 + ((wave&1)<<6);
  const int lr = lane & 15, lk = (lane >> 4) * 8;
  const int N = NT << 7;
  f32x4 acc[4][4] = {};
  const u16* Ab = A + (long)row0*K + lk;
  const u16* Wb = W + (long)col0*K + lk;
  for (int k0 = 0; k0 < K; k0 += 32){
    bf16x8 a[4], b[4];
    #pragma unroll
    for (int i = 0; i < 4; ++i) a[i] = *(const bf16x8*)(Ab + (long)(16*i+lr)*K + k0);
    #pragma unroll
    for (int j = 0; j < 4; ++j) b[j] = *(const bf16x8*)(Wb + (long)(16*j+lr)*K + k0);
    #pragma unroll
    for (int i = 0; i < 4; ++i)
      #pragma unroll
      for (int j = 0; j < 4; ++j)
        acc[i][j] = __builtin_amdgcn_mfma_f32_16x16x32_bf16(a[i], b[j], acc[i][j], 0, 0, 0);
  }
  double ls = 0.0;
  #pragma unroll
  for (int j = 0; j < 4; ++j){
    const int col = col0 + 16*j + lr;
    const float bv = bias[col];
    #pragma unroll
    for (int i = 0; i < 4; ++i){
      #pragma unroll
      for (int q = 0; q < 4; ++q){
        const int row = row0 + 16*i + (lane>>4)*4 + q;
        const float d = tgt[(long)row*N + col] - (acc[i][j][q] + bv);
        ls += 0.5 * (double)d * (double)d;
      }
    }
  }
  ls = wave_sum_d(ls);
  if (lane == 0) atomicAdd(accp, ls);
}

// reward head over one 4096-row chunk.
__global__ void __launch_bounds__(512) rp_loss_b(const u16* __restrict__ h2,
                                                 const float* __restrict__ W2,
                                                 const float* __restrict__ b2,
                                                 const float* __restrict__ reward,
                                                 double* accp)
{
  const int tid = threadIdx.x;
  const int lane = tid & 63;
  const int wid = blockIdx.x*8 + (tid >> 6);
  double ls = 0.0;
  for (int row = wid; row < 4096; row += 2048) {
    const uint4 hv = *(const uint4*)(h2 + (long)row*FEAT_ + lane*8);
    const float4 w0 = ld4(W2 + lane*8);
    const float4 w1 = ld4(W2 + lane*8 + 4);
    float part = blo(hv.x)*w0.x + bhi(hv.x)*w0.y + blo(hv.y)*w0.z + bhi(hv.y)*w0.w
               + blo(hv.z)*w1.x + bhi(hv.z)*w1.y + blo(hv.w)*w1.z + bhi(hv.w)*w1.w;
    #pragma unroll
    for (int o = 32; o > 0; o >>= 1) part += __shfl_down(part, o, 64);
    if (lane == 0) {
      const float mu = part + b2[0];
      const float d = reward[row] - mu;
      ls += 0.5 * (double)d * (double)d;
    }
  }
  if (lane == 0) atomicAdd(accp, ls);
}

__global__ void final_k(const double* acc, float* out)
{
  const double tot = (acc[0] + acc[1] + acc[2]) / (double)(T_STEPS * B_)
                   + 512.0 * LOG2PI_ + 0.5 * LOG2PI_;
  out[0] = (float)tot;
}

extern "C" void kernel_launch(void* const* d_in, const int* in_sizes, int n_in,
                              void* d_out, int out_size, void* d_ws, size_t ws_size,
                              hipStream_t stream) {
  const float* emb    = (const float*)d_in[0];
  const float* action = (const float*)d_in[1];
  const float* reward = (const float*)d_in[2];
  const float* eps    = (const float*)d_in[3];
  const float* Wih  = (const float*)d_in[4];  const float* bih  = (const float*)d_in[5];
  const float* Whh  = (const float*)d_in[6];  const float* bhh  = (const float*)d_in[7];
  const float* stW0 = (const float*)d_in[8];  const float* stb0 = (const float*)d_in[9];
  const float* stW1 = (const float*)d_in[10]; const float* stb1 = (const float*)d_in[11];
  const float* stW2 = (const float*)d_in[12]; const float* stb2 = (const float*)d_in[13];
  const float* epW0 = (const float*)d_in[14]; const float* epb0 = (const float*)d_in[15];
  const float* epW1 = (const float*)d_in[16]; const float* epb1 = (const float*)d_in[17];
  const float* epW2 = (const float*)d_in[18]; const float* epb2 = (const float*)d_in[19];
  const float* rpW0 = (const float*)d_in[20]; const float* rpb0 = (const float*)d_in[21];
  const float* rpW1 = (const float*)d_in[22]; const float* rpb1 = (const float*)d_in[23];
  const float* rpW2 = (const float*)d_in[24]; const float* rpb2 = (const float*)d_in[25];

  double* acc = (double*)d_ws;
  // workspace layout (~54 MiB)
  u16* states_b = (u16*)((char*)d_ws + 256);          // 16384*576*2 = 18.9 MB
  float* qraw   = (float*)(states_b + (long)16384*STATE_);  // 16384*128*4 = 8.4 MB
  u16* h1b   = (u16*)(qraw + (long)16384*128);        // 4096*512*2 = 4 MB
  u16* h2b   = h1b + (long)4096*FEAT_;                // 4 MB
  u16* pembb = h2b + (long)4096*FEAT_;                // 4096*1024*2 = 8.4 MB
  float* pr2f = (float*)(pembb + (long)4096*EMB_);    // 4096*128*4 = 2.1 MB
  u16* bw = (u16*)(pr2f + (long)4096*128);
  u16* bepW0 = bw;    bw += 294912;
  u16* bepW1 = bw;    bw += 262144;
  u16* bepW2 = bw;    bw += 524288;
  u16* bWhh  = bw;    bw += 786432;
  u16* bstW0 = bw;    bw += 786432;
  u16* bstW1 = bw;    bw += 262144;
  u16* bstW2 = bw;    bw += 65536;
  u16* bWih  = bw;    bw += 147456;
  u16* brpW0 = bw;    bw += 294912;
  u16* brpW1 = bw;    bw += 262144;

  hipMemsetAsync(d_ws, 0, 256, stream);

  convw_k<<<(294912+255)/256, 256, 0, stream>>>(epW0, bepW0, 294912);
  convw_k<<<(262144+255)/256, 256, 0, stream>>>(epW1, bepW1, 262144);
  convw_k<<<(524288+255)/256, 256, 0, stream>>>(epW2, bepW2, 524288);
  convw_k<<<(786432+255)/256, 256, 0, stream>>>(Whh,  bWhh,  786432);
  convw_k<<<(786432+255)/256, 256, 0, stream>>>(stW0, bstW0, 786432);
  convw_k<<<(262144+255)/256, 256, 0, stream>>>(stW1, bstW1, 262144);
  convw_k<<<(65536+255)/256,  256, 0, stream>>>(stW2, bstW2, 65536);
  convwih_k<<<(147456+255)/256, 256, 0, stream>>>(Wih, bWih);
  convw_k<<<(294912+255)/256, 256, 0, stream>>>(rpW0, brpW0, 294912);
  convw_k<<<(262144+255)/256, 256, 0, stream>>>(rpW1, brpW1, 262144);

  Params p;
  p.emb = emb; p.action = action; p.reward = reward; p.eps = eps;
  p.bih = bih; p.bhh = bhh;
  p.stb0 = stb0; p.stb1 = stb1; p.stb2 = stb2;
  p.epb0 = epb0; p.epb1 = epb1; p.epb2 = epb2;
  p.bWih = bWih; p.bWhh = bWhh;
  p.bstW0 = bstW0; p.bstW1 = bstW1; p.bstW2 = bstW2;
  p.bepW0 = bepW0; p.bepW1 = bepW1; p.bepW2 = bepW2;
  p.states = states_b;
  p.qraw = qraw;
  p.acc = acc;
  p.out = (float*)d_out;

  scan_kernel<<<B_, 512, 0, stream>>>(p);

  // ---- prior chain + KL (deferred from scan), chunks of 4096 rows ----
  for (int ch = 0; ch < 4; ++ch) {
    const u16* S    = states_b + (long)ch*4096*STATE_;
    const u16* Sprev= states_b + ((long)ch*4096 - 256)*STATE_;   // never deref'd when zlo masks
    const int zlo = (ch == 0) ? 256 : 0;
    gemm_h_k<<<32*4, 256, 0, stream>>>(Sprev, bepW0, epb0, h1b, 4, STATE_, 1, zlo);   // pe0
    gemm_h_k<<<32*4, 256, 0, stream>>>(h1b,   bepW1, epb1, h2b, 4, FEAT_, 1, 0);      // pe1
    gemm_h_k<<<32*8, 256, 0, stream>>>(h2b,   bepW2, epb2, pembb, 8, FEAT_, 0, 0);    // pemb
    gemm_cat_k<<<32*4, 256, 0, stream>>>(S, pembb, bstW0, stb0, h1b);                 // pr0
    gemm_h_k<<<32*4, 256, 0, stream>>>(h1b,   bstW1, stb1, h2b, 4, FEAT_, 1, 0);      // pr1
    gemm_raw_k<<<32, 256, 0, stream>>>(h2b, bstW2, stb2, pr2f);                        // pr2
    kl_k<<<512, 512, 0, stream>>>(qraw + (long)ch*4096*128, pr2f, acc);
  }
  // ---- ep chain: states -> h1 -> h2 -> emb loss ----
  for (int ch = 0; ch < 4; ++ch) {
    const u16* S = states_b + (long)ch*4096*STATE_;
    gemm_h_k<<<32*4, 256, 0, stream>>>(S,   bepW0, epb0, h1b, 4, STATE_, 1, 0);
    gemm_h_k<<<32*4, 256, 0, stream>>>(h1b, bepW1, epb1, h2b, 4, FEAT_, 1, 0);
    gemm_loss_k<<<32*8, 256, 0, stream>>>(h2b, bepW2, epb2, emb + (long)ch*4096*EMB_, 8, FEAT_, acc + 1);
  }
  // ---- rp chain ----
  for (int ch = 0; ch < 4; ++ch) {
    const u16* S = states_b + (long)ch*4096*STATE_;
    gemm_h_k<<<32*4, 256, 0, stream>>>(S,   brpW0, rpb0, h1b, 4, STATE_, 1, 0);
    gemm_h_k<<<32*4, 256, 0, stream>>>(h1b, brpW1, rpb1, h2b, 4, FEAT_, 1, 0);
    rp_loss_b<<<256, 512, 0, stream>>>(h2b, rpW2, rpb2, reward + (long)ch*4096, acc + 2);
  }
  final_k<<<1, 1, 0, stream>>>(acc, p.out);
}

// Round 6
// 4994.951 us; speedup vs baseline: 4.4188x; 1.5692x over previous
//
#include <hip/hip_runtime.h>
#include <math.h>

typedef unsigned short u16;
typedef __attribute__((ext_vector_type(8))) short bf16x8;
typedef __attribute__((ext_vector_type(4))) float f32x4;

#define T_STEPS 64
#define B_      256
#define EMB_    1024
#define ACT_    6
#define STOCH_  64
#define HID_    512
#define FEAT_   512
#define STATE_  576
#define G3      1536
#define LOG2PI_ 1.8378770664093453

struct Params {
  const float *emb,*action,*reward,*eps;
  const float *bih,*bhh,*stb0,*stb1,*stb2,*epb0,*epb1,*epb2;
  const u16 *bWih,*bWhh,*bstW0,*bstW0h,*bstW1,*bstW2,*bepW0,*bepW1,*bepW2;
  const u16 *eprec;       // bf16 [T*B][512]: precomputed emb_prev @ stW0[:,512:]^T
  u16 *states;            // bf16 [T*B][STATE_]
  float *qraw;            // [T*B][128]: qmu(64) | qstd(64, post-softplus)
  double *acc;            // [0]=kl [1]=emb [2]=reward
  float *out;
};

__device__ __forceinline__ float4 ld4(const float* p){ return *(const float4*)p; }
__device__ __forceinline__ float elu_f(float x){ return x > 0.f ? x : expm1f(x); }
__device__ __forceinline__ float sigmoid_f(float x){ return 1.f/(1.f+expf(-x)); }
__device__ __forceinline__ float softplus_f(float x){ return x > 20.f ? x : log1pf(expf(x)); }
__device__ __forceinline__ float blo(unsigned u){ return __uint_as_float(u << 16); }
__device__ __forceinline__ float bhi(unsigned u){ return __uint_as_float(u & 0xFFFF0000u); }
__device__ __forceinline__ float bf2f(u16 v){ return __uint_as_float((unsigned)v << 16); }
__device__ __forceinline__ u16 f2bf(float x){     // fp32 -> bf16 RNE
  const unsigned u = __float_as_uint(x);
  return (u16)((u + 0x7FFFu + ((u>>16)&1u)) >> 16);
}
__device__ __forceinline__ float qred(float a){   // reduce over 4-lane cluster
  a += __shfl_xor(a, 1, 64);
  a += __shfl_xor(a, 2, 64);
  return a;
}
__device__ __forceinline__ double wave_sum(double v){
  #pragma unroll
  for (int o = 32; o > 0; o >>= 1) v += __shfl_down(v, o, 64);
  return v;
}

// ---------------- weight converters (fp32 -> bf16 RNE) — R5-proven ----------------
__global__ void convw_k(const float* __restrict__ s, u16* __restrict__ d, int n){
  const int i = blockIdx.x*256 + threadIdx.x;
  if (i < n){
    const unsigned u = __float_as_uint(s[i]);
    d[i] = (u16)((u + 0x7FFFu + ((u>>16)&1u)) >> 16);
  }
}
// Wih [1536][70] -> padded [1536][96] bf16 (zero pad)
__global__ void convwih_k(const float* __restrict__ s, u16* __restrict__ d){
  const int i = blockIdx.x*256 + threadIdx.x;   // < 1536*96
  const int n = i/96, k = i%96;
  u16 r = 0;
  if (k < 70){
    const unsigned u = __float_as_uint(s[n*70 + k]);
    r = (u16)((u + 0x7FFFu + ((u>>16)&1u)) >> 16);
  }
  d[i] = r;
}
// stW0 h-head: [512][1536] -> packed [512][512] (cols 0..511)
__global__ void convw_sub_k(const float* __restrict__ s, u16* __restrict__ d){
  const int i = blockIdx.x*256 + threadIdx.x;   // < 512*512
  if (i < 512*512){
    const int n = i >> 9, k = i & 511;
    const unsigned u = __float_as_uint(s[(long)n*G3 + k]);
    d[i] = (u16)((u + 0x7FFFu + ((u>>16)&1u)) >> 16);
  }
}

// ---------------- scan GEMV cores: bf16 W via uint4 loads, fp32 x/accum ----------------
// 4-lane cluster, TWO output rows n0,n1 per pass sharing one x stream.
// lane l covers k = l*8 + 32*j; uint4 = 8 bf16: u32 low half = element k (LE).

template<int K>
__device__ __forceinline__ void gemv2b(const u16* __restrict__ W, const float* x,
                                       int n0, int n1, int l, float& y0, float& y1){
  const u16* w0 = W + (long)n0*K + l*8;
  const u16* w1 = W + (long)n1*K + l*8;
  const float* xr = x + l*8;
  float p0=0.f,p1=0.f,p2=0.f,p3=0.f, q0=0.f,q1=0.f,q2=0.f,q3=0.f;
  for (int j = 0; j < K/32; ++j){
    const uint4 a = *(const uint4*)(w0 + 32*j);
    const uint4 b = *(const uint4*)(w1 + 32*j);
    const float4 xa = ld4(xr + 32*j);
    const float4 xb = ld4(xr + 32*j + 4);
    p0 += blo(a.x)*xa.x + bhi(a.x)*xa.y;
    p1 += blo(a.y)*xa.z + bhi(a.y)*xa.w;
    p2 += blo(a.z)*xb.x + bhi(a.z)*xb.y;
    p3 += blo(a.w)*xb.z + bhi(a.w)*xb.w;
    q0 += blo(b.x)*xa.x + bhi(b.x)*xa.y;
    q1 += blo(b.y)*xa.z + bhi(b.y)*xa.w;
    q2 += blo(b.z)*xb.x + bhi(b.z)*xb.y;
    q3 += blo(b.w)*xb.z + bhi(b.w)*xb.w;
  }
  y0 = qred((p0+p1)+(p2+p3));
  y1 = qred((q0+q1)+(q2+q3));
}

// ---------------- scan kernel: 1024 thr (4 waves/SIMD), L2-resident weights --------
// R11: (a) st0's emb-tail precomputed (epre GEMM) -> scan weight stream 2.9 MB/step
// (< 4 MiB per-XCD L2); (b) 1024 threads, plain __launch_bounds__(1024) so compiler
// caps VGPR at 128 (R7's (1024,4) forced 64 -> spill storm; core needs ~88).
__global__ void __launch_bounds__(1024) scan_kernel(Params p)
{
  const int tid = threadIdx.x;
  const int r = blockIdx.x;
  const int c = tid >> 2, l = tid & 3;   // 256 clusters of 4 lanes

  __shared__ __align__(16) float hs[STATE_];   // [h(512) | s(64)]
  __shared__ __align__(16) float sa[96];       // [s(64) | a(6) | 0-pad]
  __shared__ __align__(16) float gi[G3], gh[G3];
  __shared__ __align__(16) float po0[512], po1[512];
  __shared__ __align__(16) float po2[128];

  if (tid < STATE_) hs[tid] = 0.f;
  __syncthreads();

  for (int t = 0; t < T_STEPS; ++t){
    // ---- prologue: sa = [s_{t-1} | a_t | 0] ----
    if (tid < 96){
      float v = 0.f;
      if (tid < 64)      v = hs[512 + tid];
      else if (tid < 70) v = p.action[((long)t*B_ + r)*ACT_ + (tid - 64)];
      sa[tid] = v;
    }
    __syncthreads();
    // ---- S_A: gh (3p), gi (3p) — read h/s_{t-1} ----
    #pragma unroll
    for (int ps = 0; ps < 3; ++ps){
      const int n0 = ps*512 + c, n1 = n0 + 256;
      float y0, y1;
      gemv2b<HID_>(p.bWhh, hs, n0, n1, l, y0, y1);
      if (l == 0){
        gh[n0] = y0 + p.bhh[n0];
        gh[n1] = y1 + p.bhh[n1];
      }
    }
    #pragma unroll
    for (int ps = 0; ps < 3; ++ps){
      const int n0 = ps*512 + c, n1 = n0 + 256;
      float y0, y1;
      gemv2b<96>(p.bWih, sa, n0, n1, l, y0, y1);
      if (l == 0){
        gi[n0] = y0 + p.bih[n0];
        gi[n1] = y1 + p.bih[n1];
      }
    }
    __syncthreads();
    // ---- GRU combine -> h_t ----
    if (tid < 512){
      const int j = tid;
      const float ir = gi[j], iz = gi[512+j], in_ = gi[1024+j];
      const float hr = gh[j], hz = gh[512+j], hn  = gh[1024+j];
      const float rr = sigmoid_f(ir + hr);
      const float z  = sigmoid_f(iz + hz);
      const float nn = tanhf(in_ + rr*hn);
      const float hv = (1.f - z)*nn + z*hs[j];
      hs[j] = hv;
      p.states[((long)t*B_ + r)*STATE_ + j] = f2bf(hv);
    }
    __syncthreads();
    // ---- st0 posterior h-head (K=512, packed) + precomputed emb-tail ----
    {
      const int n0 = c, n1 = c + 256;
      float y0, y1;
      gemv2b<HID_>(p.bstW0h, hs, n0, n1, l, y0, y1);
      if (l == 0){
        const u16* ep = p.eprec + ((long)t*B_ + r)*512;
        po0[n0] = elu_f(y0 + p.stb0[n0] + bf2f(ep[n0]));
        po0[n1] = elu_f(y1 + p.stb0[n1] + bf2f(ep[n1]));
      }
    }
    __syncthreads();
    // ---- st1 posterior (1p) ----
    {
      const int n0 = c, n1 = c + 256;
      float y0, y1;
      gemv2b<FEAT_>(p.bstW1, po0, n0, n1, l, y0, y1);
      if (l == 0){
        po1[n0] = elu_f(y0 + p.stb1[n0]);
        po1[n1] = elu_f(y1 + p.stb1[n1]);
      }
    }
    __syncthreads();
    // ---- st2 posterior (clusters 0..63) ----
    if (c < 64){
      const int n0 = c, n1 = c + 64;
      float y0, y1;
      gemv2b<FEAT_>(p.bstW2, po1, n0, n1, l, y0, y1);
      if (l == 0){
        po2[n0] = y0 + p.stb2[n0];
        po2[n1] = y1 + p.stb2[n1];
      }
    }
    __syncthreads();
    // ---- sample s_t, store qmu/qstd ----
    if (tid < 64){
      const int j = tid;
      const float qmu = po2[j],  qsr = po2[64+j];
      const float qstd = softplus_f(qsr) + 1e-4f;
      const float sv = qmu + qstd * p.eps[((long)t*B_ + r)*STOCH_ + j];
      hs[512 + j] = sv;
      p.states[((long)t*B_ + r)*STATE_ + 512 + j] = f2bf(sv);
      p.qraw[((long)t*B_ + r)*128 + j]      = qmu;
      p.qraw[((long)t*B_ + r)*128 + 64 + j] = qstd;
    }
    __syncthreads();
  }
}

// ---------------- epre GEMM: emb_prev (fp32, in-reg cvt) @ stW0[:,512:]^T -> bf16 ----
__global__ void __launch_bounds__(256) gemm_epre_k(const float* __restrict__ E,
                                                   const u16* __restrict__ W,   // bstW0 full
                                                   u16* __restrict__ Y)
{
  const int NT = 4;
  const int tid = threadIdx.x;
  const int wave = tid >> 6, lane = tid & 63;
  const int bm = blockIdx.x / NT, bn = blockIdx.x % NT;
  const int row0 = bm*128 + ((wave>>1)<<6);
  const int col0 = bn*128 + ((wave&1)<<6);
  const int lr = lane & 15, lk = (lane >> 4) * 8;
  f32x4 acc[4][4] = {};
  for (int k0 = 0; k0 < EMB_; k0 += 32){
    bf16x8 a[4], b[4];
    #pragma unroll
    for (int i = 0; i < 4; ++i){
      const int row = row0 + 16*i + lr;
      const int arow = row - (row >= B_ ? B_ : 0);   // emb_prev shift (128-blocks never straddle)
      const float* src = E + (long)arow*EMB_ + k0 + lk;
      const float4 f0 = ld4(src), f1 = ld4(src + 4);
      bf16x8 v;
      v[0] = (short)f2bf(f0.x); v[1] = (short)f2bf(f0.y);
      v[2] = (short)f2bf(f0.z); v[3] = (short)f2bf(f0.w);
      v[4] = (short)f2bf(f1.x); v[5] = (short)f2bf(f1.y);
      v[6] = (short)f2bf(f1.z); v[7] = (short)f2bf(f1.w);
      a[i] = v;
    }
    #pragma unroll
    for (int j = 0; j < 4; ++j)
      b[j] = *(const bf16x8*)(W + (long)(col0+16*j+lr)*G3 + 512 + k0 + lk);
    #pragma unroll
    for (int i = 0; i < 4; ++i)
      #pragma unroll
      for (int j = 0; j < 4; ++j)
        acc[i][j] = __builtin_amdgcn_mfma_f32_16x16x32_bf16(a[i], b[j], acc[i][j], 0, 0, 0);
  }
  #pragma unroll
  for (int j = 0; j < 4; ++j){
    const int col = col0 + 16*j + lr;
    #pragma unroll
    for (int i = 0; i < 4; ++i)
      #pragma unroll
      for (int q = 0; q < 4; ++q){
        const int row = row0 + 16*i + (lane>>4)*4 + q;
        Y[(long)row*512 + col] = f2bf(acc[i][j][q]);
      }
  }
}

// ---------------- MFMA bf16 tail GEMMs (R10-proven, byte-identical) -----------------

__global__ void __launch_bounds__(256) gemm_h_k(const u16* __restrict__ A,
                                                const u16* __restrict__ W,
                                                const float* __restrict__ bias,
                                                u16* __restrict__ Y,
                                                int NT, int K, int act, int zlo)
{
  const int tid = threadIdx.x;
  const int wave = tid >> 6, lane = tid & 63;
  const int bm = blockIdx.x / NT, bn = blockIdx.x % NT;
  const int row0 = bm*128 + ((wave>>1)<<6);
  const int col0 = bn*128 + ((wave&1)<<6);
  const int lr = lane & 15, lk = (lane >> 4) * 8;
  const int N = NT << 7;
  f32x4 acc[4][4] = {};
  const u16* Ab = A + (long)row0*K + lk;
  const u16* Wb = W + (long)col0*K + lk;
  const bf16x8 zf = {};
  for (int k0 = 0; k0 < K; k0 += 32){
    bf16x8 a[4], b[4];
    #pragma unroll
    for (int i = 0; i < 4; ++i)
      a[i] = (row0 + 16*i >= zlo) ? *(const bf16x8*)(Ab + (long)(16*i+lr)*K + k0) : zf;
    #pragma unroll
    for (int j = 0; j < 4; ++j) b[j] = *(const bf16x8*)(Wb + (long)(16*j+lr)*K + k0);
    #pragma unroll
    for (int i = 0; i < 4; ++i)
      #pragma unroll
      for (int j = 0; j < 4; ++j)
        acc[i][j] = __builtin_amdgcn_mfma_f32_16x16x32_bf16(a[i], b[j], acc[i][j], 0, 0, 0);
  }
  #pragma unroll
  for (int j = 0; j < 4; ++j){
    const int col = col0 + 16*j + lr;
    const float bv = bias[col];
    #pragma unroll
    for (int i = 0; i < 4; ++i){
      #pragma unroll
      for (int q = 0; q < 4; ++q){
        const int row = row0 + 16*i + (lane>>4)*4 + q;
        float v = acc[i][j][q] + bv;
        if (act) v = elu_f(v);
        Y[(long)row*N + col] = f2bf(v);
      }
    }
  }
}

// st0 prior: A = [states.h (ld 576, k<512) | pemb (ld 1024, k>=512)], W [512][1536], elu out
__global__ void __launch_bounds__(256) gemm_cat_k(const u16* __restrict__ A1,
                                                  const u16* __restrict__ A2,
                                                  const u16* __restrict__ W,
                                                  const float* __restrict__ bias,
                                                  u16* __restrict__ Y)
{
  const int NT = 4;
  const int tid = threadIdx.x;
  const int wave = tid >> 6, lane = tid & 63;
  const int bm = blockIdx.x / NT, bn = blockIdx.x % NT;
  const int row0 = bm*128 + ((wave>>1)<<6);
  const int col0 = bn*128 + ((wave&1)<<6);
  const int lr = lane & 15, lk = (lane >> 4) * 8;
  f32x4 acc[4][4] = {};
  for (int k0 = 0; k0 < G3; k0 += 32){
    bf16x8 a[4], b[4];
    #pragma unroll
    for (int i = 0; i < 4; ++i){
      const long row = row0 + 16*i + lr;
      a[i] = (k0 < 512) ? *(const bf16x8*)(A1 + row*STATE_ + k0 + lk)
                        : *(const bf16x8*)(A2 + row*EMB_ + (k0-512) + lk);
    }
    #pragma unroll
    for (int j = 0; j < 4; ++j)
      b[j] = *(const bf16x8*)(W + (long)(col0+16*j+lr)*G3 + k0 + lk);
    #pragma unroll
    for (int i = 0; i < 4; ++i)
      #pragma unroll
      for (int j = 0; j < 4; ++j)
        acc[i][j] = __builtin_amdgcn_mfma_f32_16x16x32_bf16(a[i], b[j], acc[i][j], 0, 0, 0);
  }
  #pragma unroll
  for (int j = 0; j < 4; ++j){
    const int col = col0 + 16*j + lr;
    const float bv = bias[col];
    #pragma unroll
    for (int i = 0; i < 4; ++i){
      #pragma unroll
      for (int q = 0; q < 4; ++q){
        const int row = row0 + 16*i + (lane>>4)*4 + q;
        Y[(long)row*FEAT_ + col] = f2bf(elu_f(acc[i][j][q] + bv));
      }
    }
  }
}

// st2 prior: N=128, K=512, raw f32 out (+bias, no act). grid = M/128 blocks.
__global__ void __launch_bounds__(256) gemm_raw_k(const u16* __restrict__ A,
                                                  const u16* __restrict__ W,
                                                  const float* __restrict__ bias,
                                                  float* __restrict__ Y)
{
  const int tid = threadIdx.x;
  const int wave = tid >> 6, lane = tid & 63;
  const int row0 = blockIdx.x*128 + ((wave>>1)<<6);
  const int col0 = (wave&1)<<6;
  const int lr = lane & 15, lk = (lane >> 4) * 8;
  f32x4 acc[4][4] = {};
  const u16* Ab = A + (long)row0*FEAT_ + lk;
  const u16* Wb = W + (long)col0*FEAT_ + lk;
  for (int k0 = 0; k0 < FEAT_; k0 += 32){
    bf16x8 a[4], b[4];
    #pragma unroll
    for (int i = 0; i < 4; ++i) a[i] = *(const bf16x8*)(Ab + (long)(16*i+lr)*FEAT_ + k0);
    #pragma unroll
    for (int j = 0; j < 4; ++j) b[j] = *(const bf16x8*)(Wb + (long)(16*j+lr)*FEAT_ + k0);
    #pragma unroll
    for (int i = 0; i < 4; ++i)
      #pragma unroll
      for (int j = 0; j < 4; ++j)
        acc[i][j] = __builtin_amdgcn_mfma_f32_16x16x32_bf16(a[i], b[j], acc[i][j], 0, 0, 0);
  }
  #pragma unroll
  for (int j = 0; j < 4; ++j){
    const int col = col0 + 16*j + lr;
    const float bv = bias[col];
    #pragma unroll
    for (int i = 0; i < 4; ++i){
      #pragma unroll
      for (int q = 0; q < 4; ++q){
        const int row = row0 + 16*i + (lane>>4)*4 + q;
        Y[(long)row*128 + col] = acc[i][j][q] + bv;
      }
    }
  }
}

// KL over one 4096-row chunk: q = stored qmu/qstd, pr = prior raw (pmu, psr).
__global__ void __launch_bounds__(512) kl_k(const float* __restrict__ q,
                                            const float* __restrict__ pr,
                                            double* accp)
{
  const int idx = blockIdx.x*512 + threadIdx.x;   // < 4096*64
  const int row = idx >> 6, j = idx & 63;
  const float qmu = q[row*128 + j], qstd = q[row*128 + 64 + j];
  const float pmu = pr[row*128 + j], psr = pr[row*128 + 64 + j];
  const float pstd = softplus_f(psr) + 1e-4f;
  const float dm = qmu - pmu;
  double v = (double)(logf(pstd/qstd) + (qstd*qstd + dm*dm)/(2.f*pstd*pstd) - 0.5f);
  v = wave_sum(v);
  if ((threadIdx.x & 63) == 0) atomicAdd(accp, v);
}

__device__ __forceinline__ double wave_sum_d(double v){
  #pragma unroll
  for (int o = 32; o > 0; o >>= 1) v += __shfl_down(v, o, 64);
  return v;
}

__global__ void __launch_bounds__(256) gemm_loss_k(const u16* __restrict__ A,
                                                   const u16* __restrict__ W,
                                                   const float* __restrict__ bias,
                                                   const float* __restrict__ tgt,
                                                   int NT, int K, double* accp)
{
  const int tid = threadIdx.x;
  const int wave = tid >> 6, lane = tid & 63;
  const int bm = blockIdx.x / NT, bn = blockIdx.x % NT;
  const int row0 = bm*128 + ((wave>>1)<<6);
  const int col0 = bn*128 + ((wave&1)<<6);
  const int lr = lane & 15, lk = (lane >> 4) * 8;
  const int N = NT << 7;
  f32x4 acc[4][4] = {};
  const u16* Ab = A + (long)row0*K + lk;
  const u16* Wb = W + (long)col0*K + lk;
  for (int k0 = 0; k0 < K; k0 += 32){
    bf16x8 a[4], b[4];
    #pragma unroll
    for (int i = 0; i < 4; ++i) a[i] = *(const bf16x8*)(Ab + (long)(16*i+lr)*K + k0);
    #pragma unroll
    for (int j = 0; j < 4; ++j) b[j] = *(const bf16x8*)(Wb + (long)(16*j+lr)*K + k0);
    #pragma unroll
    for (int i = 0; i < 4; ++i)
      #pragma unroll
      for (int j = 0; j < 4; ++j)
        acc[i][j] = __builtin_amdgcn_mfma_f32_16x16x32_bf16(a[i], b[j], acc[i][j], 0, 0, 0);
  }
  double ls = 0.0;
  #pragma unroll
  for (int j = 0; j < 4; ++j){
    const int col = col0 + 16*j + lr;
    const float bv = bias[col];
    #pragma unroll
    for (int i = 0; i < 4; ++i){
      #pragma unroll
      for (int q = 0; q < 4; ++q){
        const int row = row0 + 16*i + (lane>>4)*4 + q;
        const float d = tgt[(long)row*N + col] - (acc[i][j][q] + bv);
        ls += 0.5 * (double)d * (double)d;
      }
    }
  }
  ls = wave_sum_d(ls);
  if (lane == 0) atomicAdd(accp, ls);
}

// reward head over one 4096-row chunk.
__global__ void __launch_bounds__(512) rp_loss_b(const u16* __restrict__ h2,
                                                 const float* __restrict__ W2,
                                                 const float* __restrict__ b2,
                                                 const float* __restrict__ reward,
                                                 double* accp)
{
  const int tid = threadIdx.x;
  const int lane = tid & 63;
  const int wid = blockIdx.x*8 + (tid >> 6);
  double ls = 0.0;
  for (int row = wid; row < 4096; row += 2048) {
    const uint4 hv = *(const uint4*)(h2 + (long)row*FEAT_ + lane*8);
    const float4 w0 = ld4(W2 + lane*8);
    const float4 w1 = ld4(W2 + lane*8 + 4);
    float part = blo(hv.x)*w0.x + bhi(hv.x)*w0.y + blo(hv.y)*w0.z + bhi(hv.y)*w0.w
               + blo(hv.z)*w1.x + bhi(hv.z)*w1.y + blo(hv.w)*w1.z + bhi(hv.w)*w1.w;
    #pragma unroll
    for (int o = 32; o > 0; o >>= 1) part += __shfl_down(part, o, 64);
    if (lane == 0) {
      const float mu = part + b2[0];
      const float d = reward[row] - mu;
      ls += 0.5 * (double)d * (double)d;
    }
  }
  if (lane == 0) atomicAdd(accp, ls);
}

__global__ void final_k(const double* acc, float* out)
{
  const double tot = (acc[0] + acc[1] + acc[2]) / (double)(T_STEPS * B_)
                   + 512.0 * LOG2PI_ + 0.5 * LOG2PI_;
  out[0] = (float)tot;
}

extern "C" void kernel_launch(void* const* d_in, const int* in_sizes, int n_in,
                              void* d_out, int out_size, void* d_ws, size_t ws_size,
                              hipStream_t stream) {
  const float* emb    = (const float*)d_in[0];
  const float* action = (const float*)d_in[1];
  const float* reward = (const float*)d_in[2];
  const float* eps    = (const float*)d_in[3];
  const float* Wih  = (const float*)d_in[4];  const float* bih  = (const float*)d_in[5];
  const float* Whh  = (const float*)d_in[6];  const float* bhh  = (const float*)d_in[7];
  const float* stW0 = (const float*)d_in[8];  const float* stb0 = (const float*)d_in[9];
  const float* stW1 = (const float*)d_in[10]; const float* stb1 = (const float*)d_in[11];
  const float* stW2 = (const float*)d_in[12]; const float* stb2 = (const float*)d_in[13];
  const float* epW0 = (const float*)d_in[14]; const float* epb0 = (const float*)d_in[15];
  const float* epW1 = (const float*)d_in[16]; const float* epb1 = (const float*)d_in[17];
  const float* epW2 = (const float*)d_in[18]; const float* epb2 = (const float*)d_in[19];
  const float* rpW0 = (const float*)d_in[20]; const float* rpb0 = (const float*)d_in[21];
  const float* rpW1 = (const float*)d_in[22]; const float* rpb1 = (const float*)d_in[23];
  const float* rpW2 = (const float*)d_in[24]; const float* rpb2 = (const float*)d_in[25];

  double* acc = (double*)d_ws;
  // workspace (~54 MiB). eprec (16.8 MB) is dead after the scan; the tail's
  // pembb(8.4)+h1b(4.2)+h2b(4.2) alias it exactly.
  u16* states_b = (u16*)((char*)d_ws + 256);               // 16384*576*2
  float* qraw   = (float*)(states_b + (long)16384*STATE_); // 16384*128*4
  u16* eprec    = (u16*)(qraw + (long)16384*128);          // 16384*512*2
  u16* pembb = eprec;                                      // 4096*1024*2 (alias)
  u16* h1b   = pembb + (long)4096*EMB_;                    // 4096*512*2 (alias)
  u16* h2b   = h1b + (long)4096*FEAT_;                     // 4096*512*2 (alias)
  float* pr2f = (float*)(eprec + (long)16384*512);         // 4096*128*4
  u16* bw = (u16*)(pr2f + (long)4096*128);
  u16* bepW0 = bw;    bw += 294912;
  u16* bepW1 = bw;    bw += 262144;
  u16* bepW2 = bw;    bw += 524288;
  u16* bWhh  = bw;    bw += 786432;
  u16* bstW0 = bw;    bw += 786432;
  u16* bstW0h= bw;    bw += 262144;
  u16* bstW1 = bw;    bw += 262144;
  u16* bstW2 = bw;    bw += 65536;
  u16* bWih  = bw;    bw += 147456;
  u16* brpW0 = bw;    bw += 294912;
  u16* brpW1 = bw;    bw += 262144;

  hipMemsetAsync(d_ws, 0, 256, stream);

  convw_k<<<(294912+255)/256, 256, 0, stream>>>(epW0, bepW0, 294912);
  convw_k<<<(262144+255)/256, 256, 0, stream>>>(epW1, bepW1, 262144);
  convw_k<<<(524288+255)/256, 256, 0, stream>>>(epW2, bepW2, 524288);
  convw_k<<<(786432+255)/256, 256, 0, stream>>>(Whh,  bWhh,  786432);
  convw_k<<<(786432+255)/256, 256, 0, stream>>>(stW0, bstW0, 786432);
  convw_sub_k<<<(262144+255)/256, 256, 0, stream>>>(stW0, bstW0h);
  convw_k<<<(262144+255)/256, 256, 0, stream>>>(stW1, bstW1, 262144);
  convw_k<<<(65536+255)/256,  256, 0, stream>>>(stW2, bstW2, 65536);
  convwih_k<<<(147456+255)/256, 256, 0, stream>>>(Wih, bWih);
  convw_k<<<(294912+255)/256, 256, 0, stream>>>(rpW0, brpW0, 294912);
  convw_k<<<(262144+255)/256, 256, 0, stream>>>(rpW1, brpW1, 262144);

  // epre = emb_prev @ stW0[:,512:]^T (bf16), all 16384 rows — before the scan
  gemm_epre_k<<<128*4, 256, 0, stream>>>(emb, bstW0, eprec);

  Params p;
  p.emb = emb; p.action = action; p.reward = reward; p.eps = eps;
  p.bih = bih; p.bhh = bhh;
  p.stb0 = stb0; p.stb1 = stb1; p.stb2 = stb2;
  p.epb0 = epb0; p.epb1 = epb1; p.epb2 = epb2;
  p.bWih = bWih; p.bWhh = bWhh;
  p.bstW0 = bstW0; p.bstW0h = bstW0h; p.bstW1 = bstW1; p.bstW2 = bstW2;
  p.bepW0 = bepW0; p.bepW1 = bepW1; p.bepW2 = bepW2;
  p.eprec = eprec;
  p.states = states_b;
  p.qraw = qraw;
  p.acc = acc;
  p.out = (float*)d_out;

  scan_kernel<<<B_, 1024, 0, stream>>>(p);

  // ---- prior chain + KL (deferred from scan), chunks of 4096 rows ----
  for (int ch = 0; ch < 4; ++ch) {
    const u16* S    = states_b + (long)ch*4096*STATE_;
    const u16* Sprev= states_b + ((long)ch*4096 - 256)*STATE_;   // never deref'd when zlo masks
    const int zlo = (ch == 0) ? 256 : 0;
    gemm_h_k<<<32*4, 256, 0, stream>>>(Sprev, bepW0, epb0, h1b, 4, STATE_, 1, zlo);   // pe0
    gemm_h_k<<<32*4, 256, 0, stream>>>(h1b,   bepW1, epb1, h2b, 4, FEAT_, 1, 0);      // pe1
    gemm_h_k<<<32*8, 256, 0, stream>>>(h2b,   bepW2, epb2, pembb, 8, FEAT_, 0, 0);    // pemb
    gemm_cat_k<<<32*4, 256, 0, stream>>>(S, pembb, bstW0, stb0, h1b);                 // pr0
    gemm_h_k<<<32*4, 256, 0, stream>>>(h1b,   bstW1, stb1, h2b, 4, FEAT_, 1, 0);      // pr1
    gemm_raw_k<<<32, 256, 0, stream>>>(h2b, bstW2, stb2, pr2f);                        // pr2
    kl_k<<<512, 512, 0, stream>>>(qraw + (long)ch*4096*128, pr2f, acc);
  }
  // ---- ep chain: states -> h1 -> h2 -> emb loss ----
  for (int ch = 0; ch < 4; ++ch) {
    const u16* S = states_b + (long)ch*4096*STATE_;
    gemm_h_k<<<32*4, 256, 0, stream>>>(S,   bepW0, epb0, h1b, 4, STATE_, 1, 0);
    gemm_h_k<<<32*4, 256, 0, stream>>>(h1b, bepW1, epb1, h2b, 4, FEAT_, 1, 0);
    gemm_loss_k<<<32*8, 256, 0, stream>>>(h2b, bepW2, epb2, emb + (long)ch*4096*EMB_, 8, FEAT_, acc + 1);
  }
  // ---- rp chain ----
  for (int ch = 0; ch < 4; ++ch) {
    const u16* S = states_b + (long)ch*4096*STATE_;
    gemm_h_k<<<32*4, 256, 0, stream>>>(S,   brpW0, rpb0, h1b, 4, STATE_, 1, 0);
    gemm_h_k<<<32*4, 256, 0, stream>>>(h1b, brpW1, rpb1, h2b, 4, FEAT_, 1, 0);
    rp_loss_b<<<256, 512, 0, stream>>>(h2b, rpW2, rpb2, reward + (long)ch*4096, acc + 2);
  }
  final_k<<<1, 1, 0, stream>>>(acc, p.out);
}

// Round 7
// 4376.032 us; speedup vs baseline: 5.0438x; 1.1414x over previous
//
#include <hip/hip_runtime.h>
#include <math.h>

typedef unsigned short u16;
typedef __attribute__((ext_vector_type(8))) short bf16x8;
typedef __attribute__((ext_vector_type(4))) float f32x4;
typedef __attribute__((ext_vector_type(2))) _Float16 f16x2;

#define T_STEPS 64
#define B_      256
#define EMB_    1024
#define ACT_    6
#define STOCH_  64
#define HID_    512
#define FEAT_   512
#define STATE_  576
#define G3      1536
#define LOG2PI_ 1.8378770664093453

struct Params {
  const float *emb,*action,*reward,*eps;
  const float *bih,*bhh,*stb0,*stb1,*stb2,*epb0,*epb1,*epb2;
  const u16 *hWih,*hWhh,*hstW0h,*hstW1,*hstW2;   // f16 scan weights
  const u16 *eprec;       // bf16 [T*B][512]: precomputed emb_prev @ stW0[:,512:]^T
  u16 *states;            // bf16 [T*B][STATE_]
  float *qraw;            // [T*B][128]: qmu(64) | qstd(64, post-softplus)
  double *acc;            // [0]=kl [1]=emb [2]=reward
  float *out;
};

__device__ __forceinline__ float4 ld4(const float* p){ return *(const float4*)p; }
__device__ __forceinline__ float elu_f(float x){ return x > 0.f ? x : expm1f(x); }
__device__ __forceinline__ float sigmoid_f(float x){ return 1.f/(1.f+expf(-x)); }
__device__ __forceinline__ float softplus_f(float x){ return x > 20.f ? x : log1pf(expf(x)); }
__device__ __forceinline__ float blo(unsigned u){ return __uint_as_float(u << 16); }
__device__ __forceinline__ float bhi(unsigned u){ return __uint_as_float(u & 0xFFFF0000u); }
__device__ __forceinline__ float bf2f(u16 v){ return __uint_as_float((unsigned)v << 16); }
__device__ __forceinline__ u16 f2bf(float x){     // fp32 -> bf16 RNE
  const unsigned u = __float_as_uint(x);
  return (u16)((u + 0x7FFFu + ((u>>16)&1u)) >> 16);
}
__device__ __forceinline__ u16 f2h(float x){ _Float16 h = (_Float16)x; union{_Float16 h; u16 u;} c; c.h = h; return c.u; }
__device__ __forceinline__ float h2f(u16 v){ union{u16 u; _Float16 h;} c; c.u = v; return (float)c.h; }
__device__ __forceinline__ f16x2 asf2(unsigned u){ union{unsigned u; f16x2 v;} c; c.u = u; return c.v; }
__device__ __forceinline__ float qred(float a){   // reduce over 4-lane cluster
  a += __shfl_xor(a, 1, 64);
  a += __shfl_xor(a, 2, 64);
  return a;
}
__device__ __forceinline__ double wave_sum(double v){
  #pragma unroll
  for (int o = 32; o > 0; o >>= 1) v += __shfl_down(v, o, 64);
  return v;
}

// ---------------- weight converters ----------------
__global__ void convw_k(const float* __restrict__ s, u16* __restrict__ d, int n){
  const int i = blockIdx.x*256 + threadIdx.x;
  if (i < n){
    const unsigned u = __float_as_uint(s[i]);
    d[i] = (u16)((u + 0x7FFFu + ((u>>16)&1u)) >> 16);
  }
}
// fp32 -> f16 (RNE)
__global__ void convh_k(const float* __restrict__ s, u16* __restrict__ d, int n){
  const int i = blockIdx.x*256 + threadIdx.x;
  if (i < n) d[i] = f2h(s[i]);
}
// Wih [1536][70] -> padded [1536][96] f16 (zero pad)
__global__ void convhih_k(const float* __restrict__ s, u16* __restrict__ d){
  const int i = blockIdx.x*256 + threadIdx.x;   // < 1536*96
  const int n = i/96, k = i%96;
  d[i] = (k < 70) ? f2h(s[n*70 + k]) : (u16)0;
}
// stW0 h-head: [512][1536] -> packed [512][512] f16 (cols 0..511)
__global__ void convh_sub_k(const float* __restrict__ s, u16* __restrict__ d){
  const int i = blockIdx.x*256 + threadIdx.x;   // < 512*512
  if (i < 512*512){
    const int n = i >> 9, k = i & 511;
    d[i] = f2h(s[(long)n*G3 + k]);
  }
}

// ---------------- scan GEMV core: f16 W & x via v_dot2_f32_f16 ----------------
// 4-lane cluster, TWO output rows n0,n1 sharing one x stream.
// lane l covers k = l*8 + 32*j; uint4 = 8 f16. fdot2: 2 MACs/instr, f32 accum.
template<int K>
__device__ __forceinline__ void gemv2h(const u16* __restrict__ W, const u16* __restrict__ x,
                                       int n0, int n1, int l, float& y0, float& y1){
  const u16* w0 = W + (long)n0*K + l*8;
  const u16* w1 = W + (long)n1*K + l*8;
  const u16* xr = x + l*8;
  float a0=0.f, a1=0.f, b0=0.f, b1=0.f;
  for (int j = 0; j < K/32; ++j){
    const uint4 a  = *(const uint4*)(w0 + 32*j);
    const uint4 b  = *(const uint4*)(w1 + 32*j);
    const uint4 xv = *(const uint4*)(xr + 32*j);
    a0 = __builtin_amdgcn_fdot2(asf2(a.x), asf2(xv.x), a0, false);
    a1 = __builtin_amdgcn_fdot2(asf2(a.y), asf2(xv.y), a1, false);
    a0 = __builtin_amdgcn_fdot2(asf2(a.z), asf2(xv.z), a0, false);
    a1 = __builtin_amdgcn_fdot2(asf2(a.w), asf2(xv.w), a1, false);
    b0 = __builtin_amdgcn_fdot2(asf2(b.x), asf2(xv.x), b0, false);
    b1 = __builtin_amdgcn_fdot2(asf2(b.y), asf2(xv.y), b1, false);
    b0 = __builtin_amdgcn_fdot2(asf2(b.z), asf2(xv.z), b0, false);
    b1 = __builtin_amdgcn_fdot2(asf2(b.w), asf2(xv.w), b1, false);
  }
  y0 = qred(a0 + a1);
  y1 = qred(b0 + b1);
}

// ---------------- scan kernel: 1024 thr, f16 fdot2 core (R12) ----------------------
// R11 structure (proven 3455 us, occ 48%); activations in LDS as f16 (10-bit mantissa,
// strictly better than R9's all-bf16 which passed), weights f16, fp32 accum via fdot2.
__global__ void __launch_bounds__(1024) scan_kernel(Params p)
{
  const int tid = threadIdx.x;
  const int r = blockIdx.x;
  const int c = tid >> 2, l = tid & 3;   // 256 clusters of 4 lanes

  __shared__ __align__(16) u16 hsh[STATE_];    // f16 [h(512) | s(64)]
  __shared__ __align__(16) u16 sah[96];        // f16 [s(64) | a(6) | 0-pad]
  __shared__ __align__(16) float gi[G3], gh[G3];
  __shared__ __align__(16) u16 po0h[512], po1h[512];   // f16
  __shared__ __align__(16) float po2[128];

  if (tid < STATE_) hsh[tid] = 0;
  __syncthreads();

  for (int t = 0; t < T_STEPS; ++t){
    // ---- prologue: sa = [s_{t-1} | a_t | 0] (f16) ----
    if (tid < 96){
      u16 v = 0;
      if (tid < 64)      v = hsh[512 + tid];
      else if (tid < 70) v = f2h(p.action[((long)t*B_ + r)*ACT_ + (tid - 64)]);
      sah[tid] = v;
    }
    __syncthreads();
    // ---- gh (3p), gi (3p) ----
    #pragma unroll
    for (int ps = 0; ps < 3; ++ps){
      const int n0 = ps*512 + c, n1 = n0 + 256;
      float y0, y1;
      gemv2h<HID_>(p.hWhh, hsh, n0, n1, l, y0, y1);
      if (l == 0){
        gh[n0] = y0 + p.bhh[n0];
        gh[n1] = y1 + p.bhh[n1];
      }
    }
    #pragma unroll
    for (int ps = 0; ps < 3; ++ps){
      const int n0 = ps*512 + c, n1 = n0 + 256;
      float y0, y1;
      gemv2h<96>(p.hWih, sah, n0, n1, l, y0, y1);
      if (l == 0){
        gi[n0] = y0 + p.bih[n0];
        gi[n1] = y1 + p.bih[n1];
      }
    }
    __syncthreads();
    // ---- GRU combine -> h_t ----
    if (tid < 512){
      const int j = tid;
      const float ir = gi[j], iz = gi[512+j], in_ = gi[1024+j];
      const float hr = gh[j], hz = gh[512+j], hn  = gh[1024+j];
      const float rr = sigmoid_f(ir + hr);
      const float z  = sigmoid_f(iz + hz);
      const float nn = tanhf(in_ + rr*hn);
      const float hv = (1.f - z)*nn + z*h2f(hsh[j]);
      hsh[j] = f2h(hv);
      p.states[((long)t*B_ + r)*STATE_ + j] = f2bf(hv);
    }
    __syncthreads();
    // ---- st0 posterior h-head (K=512, packed f16) + precomputed emb-tail ----
    {
      const int n0 = c, n1 = c + 256;
      float y0, y1;
      gemv2h<HID_>(p.hstW0h, hsh, n0, n1, l, y0, y1);
      if (l == 0){
        const u16* ep = p.eprec + ((long)t*B_ + r)*512;
        po0h[n0] = f2h(elu_f(y0 + p.stb0[n0] + bf2f(ep[n0])));
        po0h[n1] = f2h(elu_f(y1 + p.stb0[n1] + bf2f(ep[n1])));
      }
    }
    __syncthreads();
    // ---- st1 posterior ----
    {
      const int n0 = c, n1 = c + 256;
      float y0, y1;
      gemv2h<FEAT_>(p.hstW1, po0h, n0, n1, l, y0, y1);
      if (l == 0){
        po1h[n0] = f2h(elu_f(y0 + p.stb1[n0]));
        po1h[n1] = f2h(elu_f(y1 + p.stb1[n1]));
      }
    }
    __syncthreads();
    // ---- st2 posterior (clusters 0..63) ----
    if (c < 64){
      const int n0 = c, n1 = c + 64;
      float y0, y1;
      gemv2h<FEAT_>(p.hstW2, po1h, n0, n1, l, y0, y1);
      if (l == 0){
        po2[n0] = y0 + p.stb2[n0];
        po2[n1] = y1 + p.stb2[n1];
      }
    }
    __syncthreads();
    // ---- sample s_t, store qmu/qstd ----
    if (tid < 64){
      const int j = tid;
      const float qmu = po2[j],  qsr = po2[64+j];
      const float qstd = softplus_f(qsr) + 1e-4f;
      const float sv = qmu + qstd * p.eps[((long)t*B_ + r)*STOCH_ + j];
      hsh[512 + j] = f2h(sv);
      p.states[((long)t*B_ + r)*STATE_ + 512 + j] = f2bf(sv);
      p.qraw[((long)t*B_ + r)*128 + j]      = qmu;
      p.qraw[((long)t*B_ + r)*128 + 64 + j] = qstd;
    }
    __syncthreads();
  }
}

// ---------------- epre GEMM: emb_prev (fp32, in-reg cvt) @ stW0[:,512:]^T -> bf16 ----
__global__ void __launch_bounds__(256) gemm_epre_k(const float* __restrict__ E,
                                                   const u16* __restrict__ W,   // bstW0 full
                                                   u16* __restrict__ Y)
{
  const int NT = 4;
  const int tid = threadIdx.x;
  const int wave = tid >> 6, lane = tid & 63;
  const int bm = blockIdx.x / NT, bn = blockIdx.x % NT;
  const int row0 = bm*128 + ((wave>>1)<<6);
  const int col0 = bn*128 + ((wave&1)<<6);
  const int lr = lane & 15, lk = (lane >> 4) * 8;
  f32x4 acc[4][4] = {};
  for (int k0 = 0; k0 < EMB_; k0 += 32){
    bf16x8 a[4], b[4];
    #pragma unroll
    for (int i = 0; i < 4; ++i){
      const int row = row0 + 16*i + lr;
      const int arow = row - (row >= B_ ? B_ : 0);   // emb_prev shift (128-blocks never straddle)
      const float* src = E + (long)arow*EMB_ + k0 + lk;
      const float4 f0 = ld4(src), f1 = ld4(src + 4);
      bf16x8 v;
      v[0] = (short)f2bf(f0.x); v[1] = (short)f2bf(f0.y);
      v[2] = (short)f2bf(f0.z); v[3] = (short)f2bf(f0.w);
      v[4] = (short)f2bf(f1.x); v[5] = (short)f2bf(f1.y);
      v[6] = (short)f2bf(f1.z); v[7] = (short)f2bf(f1.w);
      a[i] = v;
    }
    #pragma unroll
    for (int j = 0; j < 4; ++j)
      b[j] = *(const bf16x8*)(W + (long)(col0+16*j+lr)*G3 + 512 + k0 + lk);
    #pragma unroll
    for (int i = 0; i < 4; ++i)
      #pragma unroll
      for (int j = 0; j < 4; ++j)
        acc[i][j] = __builtin_amdgcn_mfma_f32_16x16x32_bf16(a[i], b[j], acc[i][j], 0, 0, 0);
  }
  #pragma unroll
  for (int j = 0; j < 4; ++j){
    const int col = col0 + 16*j + lr;
    #pragma unroll
    for (int i = 0; i < 4; ++i)
      #pragma unroll
      for (int q = 0; q < 4; ++q){
        const int row = row0 + 16*i + (lane>>4)*4 + q;
        Y[(long)row*512 + col] = f2bf(acc[i][j][q]);
      }
  }
}

// ---------------- MFMA bf16 tail GEMMs (R10-proven, byte-identical) -----------------

__global__ void __launch_bounds__(256) gemm_h_k(const u16* __restrict__ A,
                                                const u16* __restrict__ W,
                                                const float* __restrict__ bias,
                                                u16* __restrict__ Y,
                                                int NT, int K, int act, int zlo)
{
  const int tid = threadIdx.x;
  const int wave = tid >> 6, lane = tid & 63;
  const int bm = blockIdx.x / NT, bn = blockIdx.x % NT;
  const int row0 = bm*128 + ((wave>>1)<<6);
  const int col0 = bn*128 + ((wave&1)<<6);
  const int lr = lane & 15, lk = (lane >> 4) * 8;
  const int N = NT << 7;
  f32x4 acc[4][4] = {};
  const u16* Ab = A + (long)row0*K + lk;
  const u16* Wb = W + (long)col0*K + lk;
  const bf16x8 zf = {};
  for (int k0 = 0; k0 < K; k0 += 32){
    bf16x8 a[4], b[4];
    #pragma unroll
    for (int i = 0; i < 4; ++i)
      a[i] = (row0 + 16*i >= zlo) ? *(const bf16x8*)(Ab + (long)(16*i+lr)*K + k0) : zf;
    #pragma unroll
    for (int j = 0; j < 4; ++j) b[j] = *(const bf16x8*)(Wb + (long)(16*j+lr)*K + k0);
    #pragma unroll
    for (int i = 0; i < 4; ++i)
      #pragma unroll
      for (int j = 0; j < 4; ++j)
        acc[i][j] = __builtin_amdgcn_mfma_f32_16x16x32_bf16(a[i], b[j], acc[i][j], 0, 0, 0);
  }
  #pragma unroll
  for (int j = 0; j < 4; ++j){
    const int col = col0 + 16*j + lr;
    const float bv = bias[col];
    #pragma unroll
    for (int i = 0; i < 4; ++i){
      #pragma unroll
      for (int q = 0; q < 4; ++q){
        const int row = row0 + 16*i + (lane>>4)*4 + q;
        float v = acc[i][j][q] + bv;
        if (act) v = elu_f(v);
        Y[(long)row*N + col] = f2bf(v);
      }
    }
  }
}

// st0 prior: A = [states.h (ld 576, k<512) | pemb (ld 1024, k>=512)], W [512][1536], elu out
__global__ void __launch_bounds__(256) gemm_cat_k(const u16* __restrict__ A1,
                                                  const u16* __restrict__ A2,
                                                  const u16* __restrict__ W,
                                                  const float* __restrict__ bias,
                                                  u16* __restrict__ Y)
{
  const int NT = 4;
  const int tid = threadIdx.x;
  const int wave = tid >> 6, lane = tid & 63;
  const int bm = blockIdx.x / NT, bn = blockIdx.x % NT;
  const int row0 = bm*128 + ((wave>>1)<<6);
  const int col0 = bn*128 + ((wave&1)<<6);
  const int lr = lane & 15, lk = (lane >> 4) * 8;
  f32x4 acc[4][4] = {};
  for (int k0 = 0; k0 < G3; k0 += 32){
    bf16x8 a[4], b[4];
    #pragma unroll
    for (int i = 0; i < 4; ++i){
      const long row = row0 + 16*i + lr;
      a[i] = (k0 < 512) ? *(const bf16x8*)(A1 + row*STATE_ + k0 + lk)
                        : *(const bf16x8*)(A2 + row*EMB_ + (k0-512) + lk);
    }
    #pragma unroll
    for (int j = 0; j < 4; ++j)
      b[j] = *(const bf16x8*)(W + (long)(col0+16*j+lr)*G3 + k0 + lk);
    #pragma unroll
    for (int i = 0; i < 4; ++i)
      #pragma unroll
      for (int j = 0; j < 4; ++j)
        acc[i][j] = __builtin_amdgcn_mfma_f32_16x16x32_bf16(a[i], b[j], acc[i][j], 0, 0, 0);
  }
  #pragma unroll
  for (int j = 0; j < 4; ++j){
    const int col = col0 + 16*j + lr;
    const float bv = bias[col];
    #pragma unroll
    for (int i = 0; i < 4; ++i){
      #pragma unroll
      for (int q = 0; q < 4; ++q){
        const int row = row0 + 16*i + (lane>>4)*4 + q;
        Y[(long)row*FEAT_ + col] = f2bf(elu_f(acc[i][j][q] + bv));
      }
    }
  }
}

// st2 prior: N=128, K=512, raw f32 out (+bias, no act). grid = M/128 blocks.
__global__ void __launch_bounds__(256) gemm_raw_k(const u16* __restrict__ A,
                                                  const u16* __restrict__ W,
                                                  const float* __restrict__ bias,
                                                  float* __restrict__ Y)
{
  const int tid = threadIdx.x;
  const int wave = tid >> 6, lane = tid & 63;
  const int row0 = blockIdx.x*128 + ((wave>>1)<<6);
  const int col0 = (wave&1)<<6;
  const int lr = lane & 15, lk = (lane >> 4) * 8;
  f32x4 acc[4][4] = {};
  const u16* Ab = A + (long)row0*FEAT_ + lk;
  const u16* Wb = W + (long)col0*FEAT_ + lk;
  for (int k0 = 0; k0 < FEAT_; k0 += 32){
    bf16x8 a[4], b[4];
    #pragma unroll
    for (int i = 0; i < 4; ++i) a[i] = *(const bf16x8*)(Ab + (long)(16*i+lr)*FEAT_ + k0);
    #pragma unroll
    for (int j = 0; j < 4; ++j) b[j] = *(const bf16x8*)(Wb + (long)(16*j+lr)*FEAT_ + k0);
    #pragma unroll
    for (int i = 0; i < 4; ++i)
      #pragma unroll
      for (int j = 0; j < 4; ++j)
        acc[i][j] = __builtin_amdgcn_mfma_f32_16x16x32_bf16(a[i], b[j], acc[i][j], 0, 0, 0);
  }
  #pragma unroll
  for (int j = 0; j < 4; ++j){
    const int col = col0 + 16*j + lr;
    const float bv = bias[col];
    #pragma unroll
    for (int i = 0; i < 4; ++i){
      #pragma unroll
      for (int q = 0; q < 4; ++q){
        const int row = row0 + 16*i + (lane>>4)*4 + q;
        Y[(long)row*128 + col] = acc[i][j][q] + bv;
      }
    }
  }
}

// KL over one 4096-row chunk: q = stored qmu/qstd, pr = prior raw (pmu, psr).
__global__ void __launch_bounds__(512) kl_k(const float* __restrict__ q,
                                            const float* __restrict__ pr,
                                            double* accp)
{
  const int idx = blockIdx.x*512 + threadIdx.x;   // < 4096*64
  const int row = idx >> 6, j = idx & 63;
  const float qmu = q[row*128 + j], qstd = q[row*128 + 64 + j];
  const float pmu = pr[row*128 + j], psr = pr[row*128 + 64 + j];
  const float pstd = softplus_f(psr) + 1e-4f;
  const float dm = qmu - pmu;
  double v = (double)(logf(pstd/qstd) + (qstd*qstd + dm*dm)/(2.f*pstd*pstd) - 0.5f);
  v = wave_sum(v);
  if ((threadIdx.x & 63) == 0) atomicAdd(accp, v);
}

__device__ __forceinline__ double wave_sum_d(double v){
  #pragma unroll
  for (int o = 32; o > 0; o >>= 1) v += __shfl_down(v, o, 64);
  return v;
}

__global__ void __launch_bounds__(256) gemm_loss_k(const u16* __restrict__ A,
                                                   const u16* __restrict__ W,
                                                   const float* __restrict__ bias,
                                                   const float* __restrict__ tgt,
                                                   int NT, int K, double* accp)
{
  const int tid = threadIdx.x;
  const int wave = tid >> 6, lane = tid & 63;
  const int bm = blockIdx.x / NT, bn = blockIdx.x % NT;
  const int row0 = bm*128 + ((wave>>1)<<6);
  const int col0 = bn*128 + ((wave&1)<<6);
  const int lr = lane & 15, lk = (lane >> 4) * 8;
  const int N = NT << 7;
  f32x4 acc[4][4] = {};
  const u16* Ab = A + (long)row0*K + lk;
  const u16* Wb = W + (long)col0*K + lk;
  for (int k0 = 0; k0 < K; k0 += 32){
    bf16x8 a[4], b[4];
    #pragma unroll
    for (int i = 0; i < 4; ++i) a[i] = *(const bf16x8*)(Ab + (long)(16*i+lr)*K + k0);
    #pragma unroll
    for (int j = 0; j < 4; ++j) b[j] = *(const bf16x8*)(Wb + (long)(16*j+lr)*K + k0);
    #pragma unroll
    for (int i = 0; i < 4; ++i)
      #pragma unroll
      for (int j = 0; j < 4; ++j)
        acc[i][j] = __builtin_amdgcn_mfma_f32_16x16x32_bf16(a[i], b[j], acc[i][j], 0, 0, 0);
  }
  double ls = 0.0;
  #pragma unroll
  for (int j = 0; j < 4; ++j){
    const int col = col0 + 16*j + lr;
    const float bv = bias[col];
    #pragma unroll
    for (int i = 0; i < 4; ++i){
      #pragma unroll
      for (int q = 0; q < 4; ++q){
        const int row = row0 + 16*i + (lane>>4)*4 + q;
        const float d = tgt[(long)row*N + col] - (acc[i][j][q] + bv);
        ls += 0.5 * (double)d * (double)d;
      }
    }
  }
  ls = wave_sum_d(ls);
  if (lane == 0) atomicAdd(accp, ls);
}

// reward head over one 8192-row chunk.
__global__ void __launch_bounds__(512) rp_loss_b(const u16* __restrict__ h2,
                                                 const float* __restrict__ W2,
                                                 const float* __restrict__ b2,
                                                 const float* __restrict__ reward,
                                                 double* accp)
{
  const int tid = threadIdx.x;
  const int lane = tid & 63;
  const int wid = blockIdx.x*8 + (tid >> 6);
  double ls = 0.0;
  for (int row = wid; row < 8192; row += 2048) {
    const uint4 hv = *(const uint4*)(h2 + (long)row*FEAT_ + lane*8);
    const float4 w0 = ld4(W2 + lane*8);
    const float4 w1 = ld4(W2 + lane*8 + 4);
    float part = blo(hv.x)*w0.x + bhi(hv.x)*w0.y + blo(hv.y)*w0.z + bhi(hv.y)*w0.w
               + blo(hv.z)*w1.x + bhi(hv.z)*w1.y + blo(hv.w)*w1.z + bhi(hv.w)*w1.w;
    #pragma unroll
    for (int o = 32; o > 0; o >>= 1) part += __shfl_down(part, o, 64);
    if (lane == 0) {
      const float mu = part + b2[0];
      const float d = reward[row] - mu;
      ls += 0.5 * (double)d * (double)d;
    }
  }
  if (lane == 0) atomicAdd(accp, ls);
}

__global__ void final_k(const double* acc, float* out)
{
  const double tot = (acc[0] + acc[1] + acc[2]) / (double)(T_STEPS * B_)
                   + 512.0 * LOG2PI_ + 0.5 * LOG2PI_;
  out[0] = (float)tot;
}

extern "C" void kernel_launch(void* const* d_in, const int* in_sizes, int n_in,
                              void* d_out, int out_size, void* d_ws, size_t ws_size,
                              hipStream_t stream) {
  const float* emb    = (const float*)d_in[0];
  const float* action = (const float*)d_in[1];
  const float* reward = (const float*)d_in[2];
  const float* eps    = (const float*)d_in[3];
  const float* Wih  = (const float*)d_in[4];  const float* bih  = (const float*)d_in[5];
  const float* Whh  = (const float*)d_in[6];  const float* bhh  = (const float*)d_in[7];
  const float* stW0 = (const float*)d_in[8];  const float* stb0 = (const float*)d_in[9];
  const float* stW1 = (const float*)d_in[10]; const float* stb1 = (const float*)d_in[11];
  const float* stW2 = (const float*)d_in[12]; const float* stb2 = (const float*)d_in[13];
  const float* epW0 = (const float*)d_in[14]; const float* epb0 = (const float*)d_in[15];
  const float* epW1 = (const float*)d_in[16]; const float* epb1 = (const float*)d_in[17];
  const float* epW2 = (const float*)d_in[18]; const float* epb2 = (const float*)d_in[19];
  const float* rpW0 = (const float*)d_in[20]; const float* rpb0 = (const float*)d_in[21];
  const float* rpW1 = (const float*)d_in[22]; const float* rpb1 = (const float*)d_in[23];
  const float* rpW2 = (const float*)d_in[24]; const float* rpb2 = (const float*)d_in[25];

  double* acc = (double*)d_ws;
  // workspace (~55 MiB). eprec (16.8 MB) dead after scan; prior chunk bufs
  // (pembb 8.4 + h1b 4.2 + h2b 4.2) and ep/rp M=8192 bufs (h1c 8.4 + h2c 8.4) alias it.
  u16* states_b = (u16*)((char*)d_ws + 256);               // 16384*576*2
  float* qraw   = (float*)(states_b + (long)16384*STATE_); // 16384*128*4
  u16* eprec    = (u16*)(qraw + (long)16384*128);          // 16384*512*2
  u16* pembb = eprec;                                      // 4096*1024*2 (alias)
  u16* h1b   = pembb + (long)4096*EMB_;                    // 4096*512*2 (alias)
  u16* h2b   = h1b + (long)4096*FEAT_;                     // 4096*512*2 (alias)
  u16* h1c   = eprec;                                      // 8192*512*2 (alias)
  u16* h2c   = h1c + (long)8192*FEAT_;                     // 8192*512*2 (alias)
  float* pr2f = (float*)(eprec + (long)16384*512);         // 4096*128*4
  u16* bw = (u16*)(pr2f + (long)4096*128);
  // bf16 tail weights
  u16* bepW0 = bw;    bw += 294912;
  u16* bepW1 = bw;    bw += 262144;
  u16* bepW2 = bw;    bw += 524288;
  u16* bstW0 = bw;    bw += 786432;
  u16* bstW1 = bw;    bw += 262144;
  u16* bstW2 = bw;    bw += 65536;
  u16* brpW0 = bw;    bw += 294912;
  u16* brpW1 = bw;    bw += 262144;
  // f16 scan weights
  u16* hWhh  = bw;    bw += 786432;
  u16* hWih  = bw;    bw += 147456;
  u16* hstW0h= bw;    bw += 262144;
  u16* hstW1 = bw;    bw += 262144;
  u16* hstW2 = bw;    bw += 65536;

  hipMemsetAsync(d_ws, 0, 256, stream);

  convw_k<<<(294912+255)/256, 256, 0, stream>>>(epW0, bepW0, 294912);
  convw_k<<<(262144+255)/256, 256, 0, stream>>>(epW1, bepW1, 262144);
  convw_k<<<(524288+255)/256, 256, 0, stream>>>(epW2, bepW2, 524288);
  convw_k<<<(786432+255)/256, 256, 0, stream>>>(stW0, bstW0, 786432);
  convw_k<<<(262144+255)/256, 256, 0, stream>>>(stW1, bstW1, 262144);
  convw_k<<<(65536+255)/256,  256, 0, stream>>>(stW2, bstW2, 65536);
  convw_k<<<(294912+255)/256, 256, 0, stream>>>(rpW0, brpW0, 294912);
  convw_k<<<(262144+255)/256, 256, 0, stream>>>(rpW1, brpW1, 262144);
  convh_k<<<(786432+255)/256, 256, 0, stream>>>(Whh,  hWhh,  786432);
  convhih_k<<<(147456+255)/256, 256, 0, stream>>>(Wih, hWih);
  convh_sub_k<<<(262144+255)/256, 256, 0, stream>>>(stW0, hstW0h);
  convh_k<<<(262144+255)/256, 256, 0, stream>>>(stW1, hstW1, 262144);
  convh_k<<<(65536+255)/256,  256, 0, stream>>>(stW2, hstW2, 65536);

  // epre = emb_prev @ stW0[:,512:]^T (bf16), all 16384 rows — before the scan
  gemm_epre_k<<<128*4, 256, 0, stream>>>(emb, bstW0, eprec);

  Params p;
  p.emb = emb; p.action = action; p.reward = reward; p.eps = eps;
  p.bih = bih; p.bhh = bhh;
  p.stb0 = stb0; p.stb1 = stb1; p.stb2 = stb2;
  p.epb0 = epb0; p.epb1 = epb1; p.epb2 = epb2;
  p.hWih = hWih; p.hWhh = hWhh;
  p.hstW0h = hstW0h; p.hstW1 = hstW1; p.hstW2 = hstW2;
  p.eprec = eprec;
  p.states = states_b;
  p.qraw = qraw;
  p.acc = acc;
  p.out = (float*)d_out;

  scan_kernel<<<B_, 1024, 0, stream>>>(p);

  // ---- prior chain + KL (deferred from scan), chunks of 4096 rows ----
  for (int ch = 0; ch < 4; ++ch) {
    const u16* S    = states_b + (long)ch*4096*STATE_;
    const u16* Sprev= states_b + ((long)ch*4096 - 256)*STATE_;   // never deref'd when zlo masks
    const int zlo = (ch == 0) ? 256 : 0;
    gemm_h_k<<<32*4, 256, 0, stream>>>(Sprev, bepW0, epb0, h1b, 4, STATE_, 1, zlo);   // pe0
    gemm_h_k<<<32*4, 256, 0, stream>>>(h1b,   bepW1, epb1, h2b, 4, FEAT_, 1, 0);      // pe1
    gemm_h_k<<<32*8, 256, 0, stream>>>(h2b,   bepW2, epb2, pembb, 8, FEAT_, 0, 0);    // pemb
    gemm_cat_k<<<32*4, 256, 0, stream>>>(S, pembb, bstW0, stb0, h1b);                 // pr0
    gemm_h_k<<<32*4, 256, 0, stream>>>(h1b,   bstW1, stb1, h2b, 4, FEAT_, 1, 0);      // pr1
    gemm_raw_k<<<32, 256, 0, stream>>>(h2b, bstW2, stb2, pr2f);                        // pr2
    kl_k<<<512, 512, 0, stream>>>(qraw + (long)ch*4096*128, pr2f, acc);
  }
  // ---- ep chain: states -> h1 -> h2 -> emb loss (M=8192 chunks) ----
  for (int ch = 0; ch < 2; ++ch) {
    const u16* S = states_b + (long)ch*8192*STATE_;
    gemm_h_k<<<64*4, 256, 0, stream>>>(S,   bepW0, epb0, h1c, 4, STATE_, 1, 0);
    gemm_h_k<<<64*4, 256, 0, stream>>>(h1c, bepW1, epb1, h2c, 4, FEAT_, 1, 0);
    gemm_loss_k<<<64*8, 256, 0, stream>>>(h2c, bepW2, epb2, emb + (long)ch*8192*EMB_, 8, FEAT_, acc + 1);
  }
  // ---- rp chain (M=8192 chunks) ----
  for (int ch = 0; ch < 2; ++ch) {
    const u16* S = states_b + (long)ch*8192*STATE_;
    gemm_h_k<<<64*4, 256, 0, stream>>>(S,   brpW0, rpb0, h1c, 4, STATE_, 1, 0);
    gemm_h_k<<<64*4, 256, 0, stream>>>(h1c, brpW1, rpb1, h2c, 4, FEAT_, 1, 0);
    rp_loss_b<<<256, 512, 0, stream>>>(h2c, rpW2, rpb2, reward + (long)ch*8192, acc + 2);
  }
  final_k<<<1, 1, 0, stream>>>(acc, p.out);
}